// Round 12
// baseline (1153.038 us; speedup 1.0000x reference)
//
#include <hip/hip_runtime.h>
#include <cstddef>

// ---- problem constants ----
constexpr int kT   = 1024;
constexpr int kB   = 64;
constexpr int kDIN = 17;
constexpr int kHM  = 150;   // main hidden (per dir)
constexpr int kHH  = 128;   // hier hidden (per dir)
constexpr int kM   = 16;    // measure length
constexpr int kD2  = 300;   // 2*kHM
constexpr int kNP  = 35;
constexpr int kNK  = 15;

// ---- workspace layout (float offsets, 16-float aligned) ----
constexpr size_t OFF_RNN16  = 0;          // ushort [1024][64][320] = 10,485,760 f
constexpr size_t OFF_HV16   = 10485760;   // ushort [4096][16][256] = 8,388,608 f
constexpr size_t OFF_HSAVE  = 18874368;   // f32 [128][160] = 20,480
constexpr size_t OFF_PTPACK = 19988480;   // ushort [16][8][64][8] = 32,768 f
constexpr size_t OFF_U      = 20021248;   // [256]
constexpr size_t OFF_W      = 20021504;   // [256]
constexpr size_t OFF_C0     = 20021760;   // [16]
constexpr size_t OFF_ACC    = 20021776;   // [16] (sp,cp,sk,ck,counter)
constexpr size_t OFF_KSLOGP = 20021792;   // [4096][15]
constexpr size_t OFF_CLOG   = 20083232;   // [4096][35]
constexpr size_t OFF_BPACK  = 20318752;   // ushort [2][24][14][64][8] = 172,032 f
constexpr size_t OFF_BPACKL = 20490784;   // ushort [3][10][64][8] = 7,680 f

typedef __bf16 bf16x8 __attribute__((ext_vector_type(8)));
typedef float f32x4 __attribute__((ext_vector_type(4)));

__device__ __forceinline__ unsigned short f2bf(float f) {
  unsigned u = __float_as_uint(f);
  u += 0x7FFFu + ((u >> 16) & 1u);
  return (unsigned short)(u >> 16);
}
__device__ __forceinline__ float bf2f(unsigned short v) {
  return __uint_as_float(((unsigned)v) << 16);
}
__device__ __forceinline__ float sigm(float x) {
  return __builtin_amdgcn_rcpf(1.f + __expf(-x));
}
__device__ __forceinline__ float tanh_fast(float x) {
  return 1.f - 2.f * __builtin_amdgcn_rcpf(__expf(2.f * x) + 1.f);
}

// ---------------------------------------------------------------------------
// MEGA kernel, 4 phases of 256 steps (diagnostic: lowers top-5 visibility
// threshold to ~180 us). Phase 0 grid 213 (GRU + all preprocessing);
// phases 1-3 grid 128 (GRU only). h handed off via hsave at each boundary.
__global__ __launch_bounds__(640, 2) void k_mega(
    const float* __restrict__ x,               // [1024][64][17]
    const float* __restrict__ mWih_f, const float* __restrict__ mWhh_f,
    const float* __restrict__ mWih_b, const float* __restrict__ mWhh_b,
    const float* __restrict__ mbih_f, const float* __restrict__ mbhh_f,
    const float* __restrict__ mbih_b, const float* __restrict__ mbhh_b,
    const float* __restrict__ hWih_f, const float* __restrict__ hWhh_f,
    const float* __restrict__ hWih_b, const float* __restrict__ hWhh_b,
    const float* __restrict__ Wp,
    const float* __restrict__ Wq, const float* __restrict__ bq,
    const float* __restrict__ Wv, const float* __restrict__ bv,
    unsigned short* __restrict__ rnn16,        // [1024][64][320]
    unsigned short* __restrict__ bpack,        // [2][24][14][64][8]
    unsigned short* __restrict__ bpackL,       // [3][10][64][8]
    unsigned short* __restrict__ pp,           // ptpack [16][8][64][8]
    float* __restrict__ u, float* __restrict__ w,
    float* __restrict__ c0, float* __restrict__ acc,
    float* __restrict__ hsave,
    int t_begin, int t_end)
{
  __shared__ __align__(16) unsigned short hx[2][160];
  __shared__ __align__(16) unsigned short hist[2][16][160];
  __shared__ __align__(16) unsigned short xall[256][32];   // this phase's x rows
  const int blk = blockIdx.x;
  if (blk < 128) {
    // ---------------- main bi-GRU ----------------
    const int d = blk & 1, b = blk >> 1;
    const int tid = threadIdx.x, wv = tid >> 6, lane = tid & 63;
    const int col = lane & 15, q8 = (lane >> 4) * 8;
    for (int i = tid; i < 2 * 160; i += 640) ((unsigned short*)hx)[i] = 0;
    for (int i = tid; i < 2 * 16 * 160; i += 640) ((unsigned short*)hist)[i] = 0;
    const int rlo = d ? (kT - t_end) : t_begin;
    for (int i = tid; i < 256 * 32; i += 640) {
      const int tt = rlo + (i >> 5), c = i & 31;
      xall[i >> 5][c] = (c < kDIN) ? f2bf(x[((size_t)tt * kB + b) * kDIN + c])
                                   : (unsigned short)0;
    }
    const float* bih = d ? mbih_b : mbih_f;
    const float* bhh = d ? mbhh_b : mbhh_f;
    const float* Wihd = d ? mWih_b : mWih_f;   // [450][17]
    const float* Whhd = d ? mWhh_b : mWhh_f;   // [450][150]
    const int j = wv * 16 + col;
    const bool actv = (lane < 16) && (j < kHM);
    float br = 0.f, bz = 0.f, bnx = 0.f, bnh = 0.f;
    if (actv) {
      br  = bih[j] + bhh[j];
      bz  = bih[150 + j] + bhh[150 + j];
      bnx = bih[300 + j];
      bnh = bhh[300 + j];
    }
    // gather B-frags (vectorized float2 fast path)
    bf16x8 bw[3][6];
    const int gts[3] = { wv, 10 + wv, 20 + wv };
    const int kb = (lane >> 4) * 8;
#pragma unroll
    for (int gi = 0; gi < 3; gi++) {
      const int slot = gts[gi] * 16 + col;
      const int type = slot / 160, jh = slot - type * 160;
      const int row = type * 150 + jh;
      const bool valid = (jh < 150);
#pragma unroll
      for (int kt = 0; kt < 6; kt++) {
        union { bf16x8 v; unsigned short us[8]; } tmp;
        if (kt < 5) {
          const int k0 = kt * 32 + kb;
          if (valid && (k0 + 8 <= 150)) {
#pragma unroll
            for (int p = 0; p < 4; p++) {
              const float2 f2 = *(const float2*)&Whhd[row * 150 + k0 + 2 * p];
              tmp.us[2 * p]     = f2bf(f2.x);
              tmp.us[2 * p + 1] = f2bf(f2.y);
            }
          } else {
#pragma unroll
            for (int jj = 0; jj < 8; jj++) {
              const int k = k0 + jj;
              tmp.us[jj] = (valid && k < 150) ? f2bf(Whhd[row * 150 + k])
                                              : (unsigned short)0;
            }
          }
        } else {
#pragma unroll
          for (int jj = 0; jj < 8; jj++) {
            const int k = kb + jj;
            tmp.us[jj] = (valid && k < 17) ? f2bf(Wihd[row * 17 + k])
                                           : (unsigned short)0;
          }
        }
        bw[gi][kt] = tmp.v;
      }
    }
    float h_old = 0.f;
    if (t_begin > 0 && actv) {
      h_old = hsave[blk * 160 + j];
      hx[t_begin & 1][j] = f2bf(h_old);
    }
    __syncthreads();

    for (int t = t_begin; t < t_end; t++) {
      const int tx = d ? (kT - 1 - t) : t;
      const int buf = t & 1;
      bf16x8 afr[6];
#pragma unroll
      for (int kt = 0; kt < 5; kt++) afr[kt] = *(const bf16x8*)&hx[buf][kt * 32 + q8];
      afr[5] = *(const bf16x8*)&xall[tx - rlo][q8];
      f32x4 aR0 = (f32x4)(0.f), aR1 = (f32x4)(0.f);
      f32x4 aZ0 = (f32x4)(0.f), aZ1 = (f32x4)(0.f);
      f32x4 aN0 = (f32x4)(0.f), aN1 = (f32x4)(0.f);
      f32x4 aX  = (f32x4)(0.f);
#pragma unroll
      for (int kt = 0; kt < 6; kt++) {
        const bf16x8 af = afr[kt];
        if ((kt & 1) == 0) {
          aR0 = __builtin_amdgcn_mfma_f32_16x16x32_bf16(af, bw[0][kt], aR0, 0, 0, 0);
          aZ0 = __builtin_amdgcn_mfma_f32_16x16x32_bf16(af, bw[1][kt], aZ0, 0, 0, 0);
          aN0 = __builtin_amdgcn_mfma_f32_16x16x32_bf16(af, bw[2][kt], aN0, 0, 0, 0);
        } else if (kt < 5) {
          aR1 = __builtin_amdgcn_mfma_f32_16x16x32_bf16(af, bw[0][kt], aR1, 0, 0, 0);
          aZ1 = __builtin_amdgcn_mfma_f32_16x16x32_bf16(af, bw[1][kt], aZ1, 0, 0, 0);
          aN1 = __builtin_amdgcn_mfma_f32_16x16x32_bf16(af, bw[2][kt], aN1, 0, 0, 0);
        } else {
          aR1 = __builtin_amdgcn_mfma_f32_16x16x32_bf16(af, bw[0][5], aR1, 0, 0, 0);
          aZ1 = __builtin_amdgcn_mfma_f32_16x16x32_bf16(af, bw[1][5], aZ1, 0, 0, 0);
          aX  = __builtin_amdgcn_mfma_f32_16x16x32_bf16(af, bw[2][5], aX, 0, 0, 0);
        }
      }
      if (actv) {
        const float r = sigm(aR0[0] + aR1[0] + br);
        const float z = sigm(aZ0[0] + aZ1[0] + bz);
        const float n = tanh_fast(aX[0] + bnx + r * (aN0[0] + aN1[0] + bnh));
        h_old = (1.f - z) * n + z * h_old;
        const unsigned short us = f2bf(h_old);
        hx[buf ^ 1][j] = us;
        hist[(t >> 4) & 1][t & 15][j] = us;
      }
      __syncthreads();
      if ((t & 15) == 15) {
        const int hb = (t >> 4) & 1;
        const int toff = tid / 40, ch = tid - toff * 40;
        const int tg = t - 15 + toff;
        const int txg = d ? (kT - 1 - tg) : tg;
        *(ushort4*)&rnn16[((size_t)txg * kB + b) * 320 + d * 160 + ch * 4] =
            *(const ushort4*)&hist[hb][toff][ch * 4];
      }
    }
    if (t_end < kT && actv) hsave[blk * 160 + j] = h_old;
  } else if (blk < 199) {
    // ---------------- hier + loss weight repack (phase 0 only) ----------------
    const int sub = threadIdx.x >> 6, lane = threadIdx.x & 63;
    int bid = (blk - 128) * 10 + sub;
    if (bid >= 702) return;
    if (bid < 672) {
      const int kt = bid % 14;
      const int nt = (bid / 14) % 24;
      const int d  = bid / (14 * 24);
      const float* Wih = d ? hWih_b : hWih_f;   // [384][300]
      const float* Whh = d ? hWhh_b : hWhh_f;   // [384][128]
      const int n = nt * 16 + (lane & 15);
      const int kbase = kt * 32 + (lane >> 4) * 8;
      unsigned short* dst = bpack + ((((size_t)d * 24 + nt) * 14 + kt) * 64 + lane) * 8;
#pragma unroll
      for (int jj = 0; jj < 8; jj++) {
        const int k = kbase + jj;
        float f = 0.f;
        if (kt < 10) {
          if (k < 150) f = Wih[n * 300 + k];
          else if (k >= 160 && k < 310) f = Wih[n * 300 + (k - 10)];
        } else {
          f = Whh[n * 128 + (k - 320)];
        }
        dst[jj] = f2bf(f);
      }
    } else {
      bid -= 672;                       // 0..29 = nt*10+kt
      const int kt = bid % 10, nt = bid / 10;
      const int n = nt * 16 + (lane & 15);
      const int kbase = kt * 32 + (lane >> 4) * 8;
      unsigned short* dst = bpackL + (((size_t)bid) * 64 + lane) * 8;
#pragma unroll
      for (int jj = 0; jj < 8; jj++) {
        const int k = kbase + jj;
        float f = 0.f;
        if (n < kNP) {
          if (k < 150) f = Wp[n * 556 + k];
          else if (k >= 160 && k < 310) f = Wp[n * 556 + (k - 10)];
        }
        dst[jj] = f2bf(f);
      }
    }
  } else if (blk < 212) {
    // ---------------- ptpack direct from Wq.Wv ----------------
    const int sub = threadIdx.x >> 6, lane = threadIdx.x & 63;
    const int bid = (blk - 199) * 10 + sub;
    if (bid >= 128) return;
    const int kt = bid & 7, nt = bid >> 3;
    const int c = nt * 16 + (lane & 15);
    const int e0 = kt * 32 + (lane >> 4) * 8;
    float av[8];
#pragma unroll
    for (int jj = 0; jj < 8; jj++) av[jj] = 0.f;
    for (int a = 0; a < 256; a++) {
      const float wq = Wq[a * 256 + c];
#pragma unroll
      for (int jj = 0; jj < 8; jj++) av[jj] += wq * Wv[a * 256 + e0 + jj];
    }
    unsigned short* dst = pp + ((size_t)bid * 64 + lane) * 8;
#pragma unroll
    for (int jj = 0; jj < 8; jj++) dst[jj] = f2bf(av[jj]);
  } else {
    // ---------------- u, w, c0, acc ----------------
    const int a = threadIdx.x;
    if (a >= 256) return;
    float us = 0.f, ws = 0.f;
    for (int jj = 0; jj < 256; jj++) {
      us += Wq[jj * 256 + a] * bv[jj];
      ws += bq[jj] * Wv[jj * 256 + a];
    }
    u[a] = us; w[a] = ws;
    if (a == 0) {
      float cc = 0.f;
      for (int jj = 0; jj < 256; jj++) cc += bq[jj] * bv[jj];
      c0[0] = cc;
      acc[0] = acc[1] = acc[2] = acc[3] = acc[4] = 0.f;
    }
  }
}

// ---------------------------------------------------------------------------
// Hier bi-GRU (validated r11): register-resident B + register prefetch.
__global__ __launch_bounds__(512, 1) void k_hier_mfma(
    const unsigned short* __restrict__ rnn16,  // [1024][64][320]
    const unsigned short* __restrict__ bpack,  // [2][24][14][64][8]
    const float* __restrict__ bihf, const float* __restrict__ bhhf,
    const float* __restrict__ bihb, const float* __restrict__ bhhb,
    unsigned short* __restrict__ hv16)         // [4096][16][256]
{
  const int d = blockIdx.x & 1;
  const int bn0 = (blockIdx.x >> 1) * 16;
  const int tid = threadIdx.x;
  const int w = tid >> 6;          // 0..7
  const int lane = tid & 63;
  const int q = lane >> 4, col = lane & 15, q8 = q * 8;

  __shared__ __align__(16) unsigned short x_s[2][16][328];
  __shared__ __align__(16) unsigned short h_s[16][136];

  for (int i = tid; i < 16 * 136; i += 512) ((unsigned short*)h_s)[i] = 0;
  const float* bih = d ? bihb : bihf;
  const float* bhh = d ? bhhb : bhhf;
  const int j = w * 16 + col;      // 0..127
  const float biR  = bih[j] + bhh[j];
  const float biZ  = bih[128 + j] + bhh[128 + j];
  const float biNX = bih[256 + j];
  const float biNH = bhh[256 + j];
  float h32r[4] = {0.f, 0.f, 0.f, 0.f};

  bf16x8 bw[3][14];
  const unsigned short* bpd = bpack + (size_t)d * 24 * 14 * 64 * 8;
  const int nts[3] = { w, 8 + w, 16 + w };
#pragma unroll
  for (int gi = 0; gi < 3; gi++)
#pragma unroll
    for (int kt = 0; kt < 14; kt++)
      bw[gi][kt] = *(const bf16x8*)&bpd[(((size_t)nts[gi] * 14 + kt) * 64 + lane) * 8];

  const int i0 = tid,        r0 = i0 / 40, c0 = i0 - r0 * 40;
  const int i1 = tid + 512,  r1 = i1 / 40, c1 = i1 - r1 * 40;
  const int bnA = bn0 + r0, bbA = bnA >> 6, nnA = bnA & 63;
  const int bnB = bn0 + r1, bbB = bnB >> 6, nnB = bnB & 63;

  {  // stage m=0
    const int mx0 = d ? 15 : 0;
    *(uint4*)&x_s[0][r0][c0 * 8] =
        *(const uint4*)&rnn16[((size_t)(nnA * 16 + mx0) * 64 + bbA) * 320 + c0 * 8];
    if (tid < 128)
      *(uint4*)&x_s[0][r1][c1 * 8] =
          *(const uint4*)&rnn16[((size_t)(nnB * 16 + mx0) * 64 + bbB) * 320 + c1 * 8];
  }
  __syncthreads();

  for (int m = 0; m < kM; m++) {
    const int mx = d ? (15 - m) : m;
    const int buf = m & 1;
    uint4 pf0, pf1;
    const bool has = (m + 1 < kM);
    if (has) {
      const int mxn = d ? (15 - (m + 1)) : (m + 1);
      pf0 = *(const uint4*)&rnn16[((size_t)(nnA * 16 + mxn) * 64 + bbA) * 320 + c0 * 8];
      if (tid < 128)
        pf1 = *(const uint4*)&rnn16[((size_t)(nnB * 16 + mxn) * 64 + bbB) * 320 + c1 * 8];
    }
    f32x4 aR = (f32x4)(0.f), aZ = (f32x4)(0.f), aNX = (f32x4)(0.f), aNH = (f32x4)(0.f);
#pragma unroll
    for (int kt = 0; kt < 14; kt++) {
      const bf16x8 af = (kt < 10) ? *(const bf16x8*)&x_s[buf][col][kt * 32 + q8]
                                  : *(const bf16x8*)&h_s[col][(kt - 10) * 32 + q8];
      aR = __builtin_amdgcn_mfma_f32_16x16x32_bf16(af, bw[0][kt], aR, 0, 0, 0);
      aZ = __builtin_amdgcn_mfma_f32_16x16x32_bf16(af, bw[1][kt], aZ, 0, 0, 0);
      if (kt < 10) aNX = __builtin_amdgcn_mfma_f32_16x16x32_bf16(af, bw[2][kt], aNX, 0, 0, 0);
      else         aNH = __builtin_amdgcn_mfma_f32_16x16x32_bf16(af, bw[2][kt], aNH, 0, 0, 0);
    }
    __syncthreads();
#pragma unroll
    for (int i = 0; i < 4; i++) {
      const int row = q * 4 + i;
      const float rr = sigm(aR[i] + biR);
      const float zz = sigm(aZ[i] + biZ);
      const float nn2 = tanh_fast(aNX[i] + biNX + rr * (aNH[i] + biNH));
      const float hnew = (1.f - zz) * nn2 + zz * h32r[i];
      h32r[i] = hnew;
      const unsigned short us = f2bf(hnew);
      h_s[row][j] = us;
      hv16[((size_t)(bn0 + row) * kM + mx) * 256 + d * kHH + j] = us;
    }
    if (has) {
      *(uint4*)&x_s[buf ^ 1][r0][c0 * 8] = pf0;
      if (tid < 128) *(uint4*)&x_s[buf ^ 1][r1][c1 * 8] = pf1;
    }
    __syncthreads();
  }
}

// ---------------------------------------------------------------------------
// Fused attention + ctx-logits (validated r10/r11): 512 blocks x 8 n.
__global__ __launch_bounds__(256) void k_attn_ctx(
    const unsigned short* __restrict__ hv16, const unsigned short* __restrict__ ptpack,
    const float* __restrict__ u, const float* __restrict__ w,
    const float* __restrict__ c0p,
    const float* __restrict__ Wp, const float* __restrict__ bp,
    const float* __restrict__ Wk, const float* __restrict__ bk,
    float* __restrict__ clog, float* __restrict__ kslogp) {
  const int tid = threadIdx.x;
  const int wv = tid >> 6, lane = tid & 63, col = lane & 15, q = lane >> 4, q8 = q * 8;
  __shared__ __align__(16) unsigned short hv16s[16][264];
  __shared__ __align__(16) unsigned short Ts16[16][264];
  __shared__ __align__(16) float W2[50][260];
  __shared__ __align__(16) float cs[256];
  __shared__ __align__(16) float us[256], wss[256];
  __shared__ float pu[16][17], pw[16][17];
  __shared__ float uh[16], wh[16], SM[16];
  __shared__ float As[16][17];
  __shared__ float arr[64];
  __shared__ float bps[35], bks[15];
  const float c0 = c0p[0];
  for (int i = tid; i < 35 * 256; i += 256) { const int r = i >> 8, c = i & 255; W2[r][c] = Wp[r * 556 + 300 + c]; }
  for (int i = tid; i < 15 * 256; i += 256) { const int r = i >> 8, c = i & 255; W2[35 + r][c] = Wk[r * 256 + c]; }
  us[tid] = u[tid];
  wss[tid] = w[tid];
  if (tid < 35) bps[tid] = bp[tid];
  else if (tid < 50) bks[tid - 35] = bk[tid - 35];
  bf16x8 bpt[4][8];
#pragma unroll
  for (int i2 = 0; i2 < 4; i2++)
#pragma unroll
    for (int kt = 0; kt < 8; kt++)
      bpt[i2][kt] = *(const bf16x8*)&ptpack[((((size_t)(wv * 4 + i2)) * 8 + kt) * 64 + lane) * 8];

  const int srow = tid >> 4, sci = (tid & 15) * 16;
  { // stage n0
    const unsigned short* src = hv16 + (size_t)(blockIdx.x * 8) * 4096;
#pragma unroll
    for (int k = 0; k < 16; k += 4)
      *(ushort4*)&hv16s[srow][sci + k] = *(const ushort4*)&src[srow * 256 + sci + k];
  }
  __syncthreads();

  for (int ni = 0; ni < 8; ni++) {
    const int n = blockIdx.x * 8 + ni;
    ushort4 pf[4];
    if (ni + 1 < 8) {
      const unsigned short* src = hv16 + (size_t)(n + 1) * 4096;
#pragma unroll
      for (int k2 = 0; k2 < 4; k2++) pf[k2] = *(const ushort4*)&src[srow * 256 + sci + k2 * 4];
    }
    {  // PT GEMM via MFMA
      f32x4 acc4[4];
#pragma unroll
      for (int i2 = 0; i2 < 4; i2++) acc4[i2] = (f32x4)(0.f);
#pragma unroll
      for (int kt = 0; kt < 8; kt++) {
        const bf16x8 af = *(const bf16x8*)&hv16s[col][kt * 32 + q8];
#pragma unroll
        for (int i2 = 0; i2 < 4; i2++)
          acc4[i2] = __builtin_amdgcn_mfma_f32_16x16x32_bf16(af, bpt[i2][kt], acc4[i2], 0, 0, 0);
      }
#pragma unroll
      for (int i2 = 0; i2 < 4; i2++) {
        const int nt = wv * 4 + i2;
#pragma unroll
        for (int i = 0; i < 4; i++) Ts16[q * 4 + i][nt * 16 + col] = f2bf(acc4[i2][i]);
      }
    }
    {  // u/w partial dots (LDS sources)
      const int l = tid >> 4, s = tid & 15;
      float su = 0.f, sw = 0.f;
#pragma unroll
      for (int a0 = 0; a0 < 16; a0++) {
        const int a = s * 16 + a0;
        const float hvv = bf2f(hv16s[l][a]);
        su += hvv * us[a];
        sw += hvv * wss[a];
      }
      pu[l][s] = su; pw[l][s] = sw;
    }
    __syncthreads();
    if (tid < 16) { float s2 = 0.f; for (int s = 0; s < 16; s++) s2 += pu[tid][s]; uh[tid] = s2; }
    else if (tid < 32) { float s2 = 0.f; for (int s = 0; s < 16; s++) s2 += pw[tid - 16][s]; wh[tid - 16] = s2; }
    __syncthreads();
    if (tid < 64) {  // wave 0: score MFMA + softmax
      f32x4 sa = (f32x4)(0.f);
#pragma unroll
      for (int kt = 0; kt < 8; kt++) {
        const bf16x8 af  = *(const bf16x8*)&hv16s[col][kt * 32 + q8];
        const bf16x8 bts = *(const bf16x8*)&Ts16[col][kt * 32 + q8];
        sa = __builtin_amdgcn_mfma_f32_16x16x32_bf16(af, bts, sa, 0, 0, 0);
      }
#pragma unroll
      for (int i = 0; i < 4; i++) {
        const int l = q * 4 + i;
        float sc = sa[i] + c0 + uh[l] + wh[col];
        float mxv = sc;
#pragma unroll
        for (int o = 8; o >= 1; o >>= 1) mxv = fmaxf(mxv, __shfl_xor(mxv, o, 16));
        const float e = __expf(sc - mxv);
        float se = e;
#pragma unroll
        for (int o = 8; o >= 1; o >>= 1) se += __shfl_xor(se, o, 16);
        As[l][col] = e / se;
      }
    }
    __syncthreads();
    if (tid < 16) {
      float s = 0.f;
      for (int l2 = 0; l2 < 16; l2++) s += As[l2][tid];
      SM[tid] = s;
    }
    __syncthreads();
    {  // ctx into LDS (last read of hv16s this iteration)
      float cv = 0.f;
#pragma unroll
      for (int m2 = 0; m2 < 16; m2++) cv += SM[m2] * bf2f(hv16s[m2][tid]);
      cs[tid] = cv;
    }
    __syncthreads();
    if (ni + 1 < 8) {
#pragma unroll
      for (int k2 = 0; k2 < 4; k2++) *(ushort4*)&hv16s[srow][sci + k2 * 4] = pf[k2];
    }
    {  // ctx-logits
      const int o = tid >> 2, s = tid & 3;
      float v = 0.f;
      if (o < 50) {
        for (int k0 = 0; k0 < 64; k0 += 4) {
          const int k = s * 64 + k0;
          const float4 wq = *(const float4*)&W2[o][k];
          const float4 cq = *(const float4*)&cs[k];
          v += wq.x * cq.x + wq.y * cq.y + wq.z * cq.z + wq.w * cq.w;
        }
      }
      v += __shfl_xor(v, 1);
      v += __shfl_xor(v, 2);
      if (o < 50 && s == 0) arr[o] = v;
    }
    __syncthreads();
    if (tid < 35) clog[n * kNP + tid] = arr[tid] + bps[tid];
    if (tid >= 64 && tid < 80) {
      const int t2 = tid - 64;
      float kk = (t2 < 15) ? arr[35 + t2] + bks[t2] : -1e30f;
      float mxv = kk;
#pragma unroll
      for (int off = 8; off >= 1; off >>= 1) mxv = fmaxf(mxv, __shfl_xor(mxv, off, 16));
      const float e = (t2 < 15) ? __expf(kk - mxv) : 0.f;
      float se = e;
#pragma unroll
      for (int off = 8; off >= 1; off >>= 1) se += __shfl_xor(se, off, 16);
      if (t2 < 15) kslogp[n * kNK + t2] = kk - mxv - __logf(se);
    }
    __syncthreads();
  }
}

// ---------------------------------------------------------------------------
// Loss via MFMA, r12: A staged through LDS (coalesced uint4 row copies ->
// fixes the 4x overfetch of 640B-strided per-lane loads). 1024 blocks x 4
// waves, 1 M-tile (16 rows) per wave; ~3 blocks/CU.
__global__ __launch_bounds__(256, 2) void k_loss_mfma(
    const unsigned short* __restrict__ rnn16,  // [65536][320]
    const unsigned short* __restrict__ bpackL, // [3][10][64][8]
    const float* __restrict__ clog,            // [4096][35]
    const float* __restrict__ ks_logp,         // [4096][15]
    const int* __restrict__ pitches, const int* __restrict__ kss,
    float* __restrict__ acc, float* __restrict__ out) {
  const int tid = threadIdx.x, w = tid >> 6, lane = tid & 63;
  const int col = lane & 15, q = lane >> 4, q8 = q * 8;
  __shared__ __align__(16) unsigned short xls[64][328];
  bf16x8 bl[3][10];
#pragma unroll
  for (int nt = 0; nt < 3; nt++)
#pragma unroll
    for (int kt = 0; kt < 10; kt++)
      bl[nt][kt] = *(const bf16x8*)&bpackL[(((size_t)nt * 10 + kt) * 64 + lane) * 8];

  {  // coalesced stage of this block's 64 rows
    const size_t base = (size_t)blockIdx.x * 64;
    for (int i = tid; i < 64 * 40; i += 256) {
      const int r = i / 40, c = i - r * 40;
      *(uint4*)&xls[r][c * 8] = *(const uint4*)&rnn16[(base + r) * 320 + c * 8];
    }
  }
  __syncthreads();

  float sp = 0.f, cp = 0.f, sk = 0.f, ck = 0.f;
  {
    const int rowbase = blockIdx.x * 64 + w * 16;
    f32x4 a0 = (f32x4)(0.f), a1 = (f32x4)(0.f), a2 = (f32x4)(0.f);
#pragma unroll
    for (int kt = 0; kt < 10; kt++) {
      const bf16x8 af = *(const bf16x8*)&xls[w * 16 + col][kt * 32 + q8];
      a0 = __builtin_amdgcn_mfma_f32_16x16x32_bf16(af, bl[0][kt], a0, 0, 0, 0);
      a1 = __builtin_amdgcn_mfma_f32_16x16x32_bf16(af, bl[1][kt], a1, 0, 0, 0);
      a2 = __builtin_amdgcn_mfma_f32_16x16x32_bf16(af, bl[2][kt], a2, 0, 0, 0);
    }
#pragma unroll
    for (int i = 0; i < 4; i++) {
      const int row = rowbase + q * 4 + i;
      const int t = row >> 6, b = row & 63;
      const int bn = b * 64 + (t >> 4);
      const float lg0 = a0[i] + clog[bn * kNP + col];
      const float lg1 = a1[i] + clog[bn * kNP + 16 + col];
      const float lg2 = (col < 3) ? (a2[i] + clog[bn * kNP + 32 + col]) : -1e30f;
      float mx = fmaxf(fmaxf(lg0, lg1), lg2);
#pragma unroll
      for (int o = 8; o >= 1; o >>= 1) mx = fmaxf(mx, __shfl_xor(mx, o, 16));
      float se = __expf(lg0 - mx) + __expf(lg1 - mx) + __expf(lg2 - mx);
#pragma unroll
      for (int o = 8; o >= 1; o >>= 1) se += __shfl_xor(se, o, 16);
      const int tp = pitches[row];
      const float cand = (tp < 16) ? a0[i] : (tp < 32) ? a1[i] : a2[i];
      const float tva = __shfl(cand, (lane & 48) | (tp & 15), 64);
      if (col == 0 && tp != 34) {
        sp += (mx + __logf(se)) - (tva + clog[bn * kNP + tp]);
        cp += 1.f;
      }
      if (col == 1) {
        const int tk = kss[row];
        if (tk != 14) { sk -= ks_logp[bn * kNK + tk]; ck += 1.f; }
      }
    }
  }
#pragma unroll
  for (int o = 32; o >= 1; o >>= 1) {
    sp += __shfl_xor(sp, o, 64);
    cp += __shfl_xor(cp, o, 64);
    sk += __shfl_xor(sk, o, 64);
    ck += __shfl_xor(ck, o, 64);
  }
  if (lane == 0) {
    atomicAdd(&acc[0], sp); atomicAdd(&acc[1], cp);
    atomicAdd(&acc[2], sk); atomicAdd(&acc[3], ck);
  }
  __syncthreads();
  if (tid == 0) {
    __threadfence();
    const float done = atomicAdd(&acc[4], 1.f);
    if (done == (float)(gridDim.x - 1)) {
      const float a0 = atomicAdd(&acc[0], 0.f);
      const float a1 = atomicAdd(&acc[1], 0.f);
      const float a2 = atomicAdd(&acc[2], 0.f);
      const float a3 = atomicAdd(&acc[3], 0.f);
      out[0] = a0 / fmaxf(a1, 1.f) + a2 / fmaxf(a3, 1.f);
    }
  }
}

// ---------------------------------------------------------------------------
extern "C" void kernel_launch(void* const* d_in, const int* in_sizes, int n_in,
                              void* d_out, int out_size, void* d_ws, size_t ws_size,
                              hipStream_t stream) {
  (void)in_sizes; (void)n_in; (void)out_size; (void)ws_size;
  const float* sent    = (const float*)d_in[0];
  const int*   pitches = (const int*)d_in[1];
  const int*   kss     = (const int*)d_in[2];
  const float* mWih_f  = (const float*)d_in[5];
  const float* mWhh_f  = (const float*)d_in[6];
  const float* mbih_f  = (const float*)d_in[7];
  const float* mbhh_f  = (const float*)d_in[8];
  const float* mWih_b  = (const float*)d_in[9];
  const float* mWhh_b  = (const float*)d_in[10];
  const float* mbih_b  = (const float*)d_in[11];
  const float* mbhh_b  = (const float*)d_in[12];
  const float* hWih_f  = (const float*)d_in[13];
  const float* hWhh_f  = (const float*)d_in[14];
  const float* hbih_f  = (const float*)d_in[15];
  const float* hbhh_f  = (const float*)d_in[16];
  const float* hWih_b  = (const float*)d_in[17];
  const float* hWhh_b  = (const float*)d_in[18];
  const float* hbih_b  = (const float*)d_in[19];
  const float* hbhh_b  = (const float*)d_in[20];
  const float* Wq      = (const float*)d_in[21];
  const float* bq      = (const float*)d_in[22];
  const float* Wv      = (const float*)d_in[23];
  const float* bv      = (const float*)d_in[24];
  const float* Wp      = (const float*)d_in[25];
  const float* bp      = (const float*)d_in[26];
  const float* Wk      = (const float*)d_in[27];
  const float* bk      = (const float*)d_in[28];
  float* ws  = (float*)d_ws;
  float* out = (float*)d_out;
  unsigned short* rnn16  = (unsigned short*)(ws + OFF_RNN16);
  unsigned short* hv16   = (unsigned short*)(ws + OFF_HV16);
  unsigned short* ptpack = (unsigned short*)(ws + OFF_PTPACK);
  unsigned short* bpackL = (unsigned short*)(ws + OFF_BPACKL);
  unsigned short* bpack  = (unsigned short*)(ws + OFF_BPACK);
  float* hsave = ws + OFF_HSAVE;

  for (int ph = 0; ph < 4; ph++) {
    const int grid = (ph == 0) ? 213 : 128;
    k_mega<<<grid, 640, 0, stream>>>(sent,
                                     mWih_f, mWhh_f, mWih_b, mWhh_b,
                                     mbih_f, mbhh_f, mbih_b, mbhh_b,
                                     hWih_f, hWhh_f, hWih_b, hWhh_b, Wp,
                                     Wq, bq, Wv, bv,
                                     rnn16, bpack, bpackL, ptpack,
                                     ws + OFF_U, ws + OFF_W, ws + OFF_C0, ws + OFF_ACC,
                                     hsave, ph * 256, (ph + 1) * 256);
  }
  k_hier_mfma<<<512, 512, 0, stream>>>(rnn16, bpack,
                                       hbih_f, hbhh_f, hbih_b, hbhh_b, hv16);
  k_attn_ctx<<<512, 256, 0, stream>>>(hv16, ptpack, ws + OFF_U, ws + OFF_W,
                                      ws + OFF_C0, Wp, bp, Wk, bk,
                                      ws + OFF_CLOG, ws + OFF_KSLOGP);
  k_loss_mfma<<<1024, 256, 0, stream>>>(rnn16, bpackL, ws + OFF_CLOG, ws + OFF_KSLOGP,
                                        pitches, kss, ws + OFF_ACC, out);
}

// Round 13
// 916.212 us; speedup vs baseline: 1.2585x; 1.2585x over previous
//
#include <hip/hip_runtime.h>
#include <cstddef>

// ---- problem constants ----
constexpr int kT   = 1024;
constexpr int kB   = 64;
constexpr int kDIN = 17;
constexpr int kHM  = 150;   // main hidden (per dir)
constexpr int kHH  = 128;   // hier hidden (per dir)
constexpr int kM   = 16;    // measure length
constexpr int kD2  = 300;   // 2*kHM
constexpr int kNP  = 35;
constexpr int kNK  = 15;

// ---- workspace layout (float offsets, 16-float aligned) ----
constexpr size_t OFF_RNN16  = 0;          // ushort [1024][64][320] = 10,485,760 f
constexpr size_t OFF_HV16   = 10485760;   // ushort [4096][16][256] = 8,388,608 f
constexpr size_t OFF_HSAVE  = 18874368;   // f32 [128][160] = 20,480
constexpr size_t OFF_PART   = 18894848;   // f32 [1024][4] = 4,096 (loss partials)
constexpr size_t OFF_PTPACK = 19988480;   // ushort [16][8][64][8] = 32,768 f
constexpr size_t OFF_U      = 20021248;   // [256]
constexpr size_t OFF_W      = 20021504;   // [256]
constexpr size_t OFF_C0     = 20021760;   // [16]
constexpr size_t OFF_KSLOGP = 20021792;   // [4096][15]
constexpr size_t OFF_CLOG   = 20083232;   // [4096][35]
constexpr size_t OFF_BPACK  = 20318752;   // ushort [2][24][14][64][8] = 172,032 f
constexpr size_t OFF_BPACKL = 20490784;   // ushort [3][10][64][8] = 7,680 f

typedef __bf16 bf16x8 __attribute__((ext_vector_type(8)));
typedef float f32x4 __attribute__((ext_vector_type(4)));

__device__ __forceinline__ unsigned short f2bf(float f) {
  unsigned u = __float_as_uint(f);
  u += 0x7FFFu + ((u >> 16) & 1u);
  return (unsigned short)(u >> 16);
}
__device__ __forceinline__ float bf2f(unsigned short v) {
  return __uint_as_float(((unsigned)v) << 16);
}
__device__ __forceinline__ float sigm(float x) {
  return __builtin_amdgcn_rcpf(1.f + __expf(-x));
}
__device__ __forceinline__ float tanh_fast(float x) {
  return 1.f - 2.f * __builtin_amdgcn_rcpf(__expf(2.f * x) + 1.f);
}

// ---------------------------------------------------------------------------
// MEGA kernel, 2 phases of 512 steps (validated r11 config: 361+358 us).
// Phase 0 grid 213 (GRU + all preprocessing); phase 1 grid 128 (GRU only).
__global__ __launch_bounds__(640, 2) void k_mega(
    const float* __restrict__ x,               // [1024][64][17]
    const float* __restrict__ mWih_f, const float* __restrict__ mWhh_f,
    const float* __restrict__ mWih_b, const float* __restrict__ mWhh_b,
    const float* __restrict__ mbih_f, const float* __restrict__ mbhh_f,
    const float* __restrict__ mbih_b, const float* __restrict__ mbhh_b,
    const float* __restrict__ hWih_f, const float* __restrict__ hWhh_f,
    const float* __restrict__ hWih_b, const float* __restrict__ hWhh_b,
    const float* __restrict__ Wp,
    const float* __restrict__ Wq, const float* __restrict__ bq,
    const float* __restrict__ Wv, const float* __restrict__ bv,
    unsigned short* __restrict__ rnn16,        // [1024][64][320]
    unsigned short* __restrict__ bpack,        // [2][24][14][64][8]
    unsigned short* __restrict__ bpackL,       // [3][10][64][8]
    unsigned short* __restrict__ pp,           // ptpack [16][8][64][8]
    float* __restrict__ u, float* __restrict__ w,
    float* __restrict__ c0,
    float* __restrict__ hsave,
    int t_begin, int t_end)
{
  __shared__ __align__(16) unsigned short hx[2][160];
  __shared__ __align__(16) unsigned short hist[2][16][160];
  __shared__ __align__(16) unsigned short xall[kT][32];
  const int blk = blockIdx.x;
  if (blk < 128) {
    // ---------------- main bi-GRU ----------------
    const int d = blk & 1, b = blk >> 1;
    const int tid = threadIdx.x, wv = tid >> 6, lane = tid & 63;
    const int col = lane & 15, q8 = (lane >> 4) * 8;
    for (int i = tid; i < 2 * 160; i += 640) ((unsigned short*)hx)[i] = 0;
    for (int i = tid; i < 2 * 16 * 160; i += 640) ((unsigned short*)hist)[i] = 0;
    {  // stage only this phase's x rows
      const int rlo = d ? (kT - t_end) : t_begin;
      for (int i = tid; i < 512 * 32; i += 640) {
        const int tt = rlo + (i >> 5), c = i & 31;
        xall[tt][c] = (c < kDIN) ? f2bf(x[((size_t)tt * kB + b) * kDIN + c])
                                 : (unsigned short)0;
      }
    }
    const float* bih = d ? mbih_b : mbih_f;
    const float* bhh = d ? mbhh_b : mbhh_f;
    const float* Wihd = d ? mWih_b : mWih_f;   // [450][17]
    const float* Whhd = d ? mWhh_b : mWhh_f;   // [450][150]
    const int j = wv * 16 + col;
    const bool actv = (lane < 16) && (j < kHM);
    float br = 0.f, bz = 0.f, bnx = 0.f, bnh = 0.f;
    if (actv) {
      br  = bih[j] + bhh[j];
      bz  = bih[150 + j] + bhh[150 + j];
      bnx = bih[300 + j];
      bnh = bhh[300 + j];
    }
    // gather B-frags (vectorized float2 fast path)
    bf16x8 bw[3][6];
    const int gts[3] = { wv, 10 + wv, 20 + wv };
    const int kb = (lane >> 4) * 8;
#pragma unroll
    for (int gi = 0; gi < 3; gi++) {
      const int slot = gts[gi] * 16 + col;
      const int type = slot / 160, jh = slot - type * 160;
      const int row = type * 150 + jh;
      const bool valid = (jh < 150);
#pragma unroll
      for (int kt = 0; kt < 6; kt++) {
        union { bf16x8 v; unsigned short us[8]; } tmp;
        if (kt < 5) {
          const int k0 = kt * 32 + kb;
          if (valid && (k0 + 8 <= 150)) {
#pragma unroll
            for (int p = 0; p < 4; p++) {
              const float2 f2 = *(const float2*)&Whhd[row * 150 + k0 + 2 * p];
              tmp.us[2 * p]     = f2bf(f2.x);
              tmp.us[2 * p + 1] = f2bf(f2.y);
            }
          } else {
#pragma unroll
            for (int jj = 0; jj < 8; jj++) {
              const int k = k0 + jj;
              tmp.us[jj] = (valid && k < 150) ? f2bf(Whhd[row * 150 + k])
                                              : (unsigned short)0;
            }
          }
        } else {
#pragma unroll
          for (int jj = 0; jj < 8; jj++) {
            const int k = kb + jj;
            tmp.us[jj] = (valid && k < 17) ? f2bf(Wihd[row * 17 + k])
                                           : (unsigned short)0;
          }
        }
        bw[gi][kt] = tmp.v;
      }
    }
    float h_old = 0.f;
    if (t_begin > 0 && actv) {
      h_old = hsave[blk * 160 + j];
      hx[t_begin & 1][j] = f2bf(h_old);
    }
    __syncthreads();

    for (int t = t_begin; t < t_end; t++) {
      const int tx = d ? (kT - 1 - t) : t;
      const int buf = t & 1;
      bf16x8 afr[6];
#pragma unroll
      for (int kt = 0; kt < 5; kt++) afr[kt] = *(const bf16x8*)&hx[buf][kt * 32 + q8];
      afr[5] = *(const bf16x8*)&xall[tx][q8];
      f32x4 aR0 = (f32x4)(0.f), aR1 = (f32x4)(0.f);
      f32x4 aZ0 = (f32x4)(0.f), aZ1 = (f32x4)(0.f);
      f32x4 aN0 = (f32x4)(0.f), aN1 = (f32x4)(0.f);
      f32x4 aX  = (f32x4)(0.f);
#pragma unroll
      for (int kt = 0; kt < 6; kt++) {
        const bf16x8 af = afr[kt];
        if ((kt & 1) == 0) {
          aR0 = __builtin_amdgcn_mfma_f32_16x16x32_bf16(af, bw[0][kt], aR0, 0, 0, 0);
          aZ0 = __builtin_amdgcn_mfma_f32_16x16x32_bf16(af, bw[1][kt], aZ0, 0, 0, 0);
          aN0 = __builtin_amdgcn_mfma_f32_16x16x32_bf16(af, bw[2][kt], aN0, 0, 0, 0);
        } else if (kt < 5) {
          aR1 = __builtin_amdgcn_mfma_f32_16x16x32_bf16(af, bw[0][kt], aR1, 0, 0, 0);
          aZ1 = __builtin_amdgcn_mfma_f32_16x16x32_bf16(af, bw[1][kt], aZ1, 0, 0, 0);
          aN1 = __builtin_amdgcn_mfma_f32_16x16x32_bf16(af, bw[2][kt], aN1, 0, 0, 0);
        } else {
          aR1 = __builtin_amdgcn_mfma_f32_16x16x32_bf16(af, bw[0][5], aR1, 0, 0, 0);
          aZ1 = __builtin_amdgcn_mfma_f32_16x16x32_bf16(af, bw[1][5], aZ1, 0, 0, 0);
          aX  = __builtin_amdgcn_mfma_f32_16x16x32_bf16(af, bw[2][5], aX, 0, 0, 0);
        }
      }
      if (actv) {
        const float r = sigm(aR0[0] + aR1[0] + br);
        const float z = sigm(aZ0[0] + aZ1[0] + bz);
        const float n = tanh_fast(aX[0] + bnx + r * (aN0[0] + aN1[0] + bnh));
        h_old = (1.f - z) * n + z * h_old;
        const unsigned short us = f2bf(h_old);
        hx[buf ^ 1][j] = us;
        hist[(t >> 4) & 1][t & 15][j] = us;
      }
      __syncthreads();
      if ((t & 15) == 15) {
        const int hb = (t >> 4) & 1;
        const int toff = tid / 40, ch = tid - toff * 40;
        const int tg = t - 15 + toff;
        const int txg = d ? (kT - 1 - tg) : tg;
        *(ushort4*)&rnn16[((size_t)txg * kB + b) * 320 + d * 160 + ch * 4] =
            *(const ushort4*)&hist[hb][toff][ch * 4];
      }
    }
    if (t_end < kT && actv) hsave[blk * 160 + j] = h_old;
  } else if (blk < 199) {
    // ---------------- hier + loss weight repack (phase 0 only) ----------------
    const int sub = threadIdx.x >> 6, lane = threadIdx.x & 63;
    int bid = (blk - 128) * 10 + sub;
    if (bid >= 702) return;
    if (bid < 672) {
      const int kt = bid % 14;
      const int nt = (bid / 14) % 24;
      const int d  = bid / (14 * 24);
      const float* Wih = d ? hWih_b : hWih_f;   // [384][300]
      const float* Whh = d ? hWhh_b : hWhh_f;   // [384][128]
      const int n = nt * 16 + (lane & 15);
      const int kbase = kt * 32 + (lane >> 4) * 8;
      unsigned short* dst = bpack + ((((size_t)d * 24 + nt) * 14 + kt) * 64 + lane) * 8;
#pragma unroll
      for (int jj = 0; jj < 8; jj++) {
        const int k = kbase + jj;
        float f = 0.f;
        if (kt < 10) {
          if (k < 150) f = Wih[n * 300 + k];
          else if (k >= 160 && k < 310) f = Wih[n * 300 + (k - 10)];
        } else {
          f = Whh[n * 128 + (k - 320)];
        }
        dst[jj] = f2bf(f);
      }
    } else {
      bid -= 672;                       // 0..29 = nt*10+kt
      const int kt = bid % 10, nt = bid / 10;
      const int n = nt * 16 + (lane & 15);
      const int kbase = kt * 32 + (lane >> 4) * 8;
      unsigned short* dst = bpackL + (((size_t)bid) * 64 + lane) * 8;
#pragma unroll
      for (int jj = 0; jj < 8; jj++) {
        const int k = kbase + jj;
        float f = 0.f;
        if (n < kNP) {
          if (k < 150) f = Wp[n * 556 + k];
          else if (k >= 160 && k < 310) f = Wp[n * 556 + (k - 10)];
        }
        dst[jj] = f2bf(f);
      }
    }
  } else if (blk < 212) {
    // ---------------- ptpack direct from Wq.Wv ----------------
    const int sub = threadIdx.x >> 6, lane = threadIdx.x & 63;
    const int bid = (blk - 199) * 10 + sub;
    if (bid >= 128) return;
    const int kt = bid & 7, nt = bid >> 3;
    const int c = nt * 16 + (lane & 15);
    const int e0 = kt * 32 + (lane >> 4) * 8;
    float av[8];
#pragma unroll
    for (int jj = 0; jj < 8; jj++) av[jj] = 0.f;
    for (int a = 0; a < 256; a++) {
      const float wq = Wq[a * 256 + c];
#pragma unroll
      for (int jj = 0; jj < 8; jj++) av[jj] += wq * Wv[a * 256 + e0 + jj];
    }
    unsigned short* dst = pp + ((size_t)bid * 64 + lane) * 8;
#pragma unroll
    for (int jj = 0; jj < 8; jj++) dst[jj] = f2bf(av[jj]);
  } else {
    // ---------------- u, w, c0 ----------------
    const int a = threadIdx.x;
    if (a >= 256) return;
    float us = 0.f, ws = 0.f;
    for (int jj = 0; jj < 256; jj++) {
      us += Wq[jj * 256 + a] * bv[jj];
      ws += bq[jj] * Wv[jj * 256 + a];
    }
    u[a] = us; w[a] = ws;
    if (a == 0) {
      float cc = 0.f;
      for (int jj = 0; jj < 256; jj++) cc += bq[jj] * bv[jj];
      c0[0] = cc;
    }
  }
}

// ---------------------------------------------------------------------------
// Hier bi-GRU (validated r11): register-resident B + register prefetch.
__global__ __launch_bounds__(512, 1) void k_hier_mfma(
    const unsigned short* __restrict__ rnn16,  // [1024][64][320]
    const unsigned short* __restrict__ bpack,  // [2][24][14][64][8]
    const float* __restrict__ bihf, const float* __restrict__ bhhf,
    const float* __restrict__ bihb, const float* __restrict__ bhhb,
    unsigned short* __restrict__ hv16)         // [4096][16][256]
{
  const int d = blockIdx.x & 1;
  const int bn0 = (blockIdx.x >> 1) * 16;
  const int tid = threadIdx.x;
  const int w = tid >> 6;          // 0..7
  const int lane = tid & 63;
  const int q = lane >> 4, col = lane & 15, q8 = q * 8;

  __shared__ __align__(16) unsigned short x_s[2][16][328];
  __shared__ __align__(16) unsigned short h_s[16][136];

  for (int i = tid; i < 16 * 136; i += 512) ((unsigned short*)h_s)[i] = 0;
  const float* bih = d ? bihb : bihf;
  const float* bhh = d ? bhhb : bhhf;
  const int j = w * 16 + col;      // 0..127
  const float biR  = bih[j] + bhh[j];
  const float biZ  = bih[128 + j] + bhh[128 + j];
  const float biNX = bih[256 + j];
  const float biNH = bhh[256 + j];
  float h32r[4] = {0.f, 0.f, 0.f, 0.f};

  bf16x8 bw[3][14];
  const unsigned short* bpd = bpack + (size_t)d * 24 * 14 * 64 * 8;
  const int nts[3] = { w, 8 + w, 16 + w };
#pragma unroll
  for (int gi = 0; gi < 3; gi++)
#pragma unroll
    for (int kt = 0; kt < 14; kt++)
      bw[gi][kt] = *(const bf16x8*)&bpd[(((size_t)nts[gi] * 14 + kt) * 64 + lane) * 8];

  const int i0 = tid,        r0 = i0 / 40, c0 = i0 - r0 * 40;
  const int i1 = tid + 512,  r1 = i1 / 40, c1 = i1 - r1 * 40;
  const int bnA = bn0 + r0, bbA = bnA >> 6, nnA = bnA & 63;
  const int bnB = bn0 + r1, bbB = bnB >> 6, nnB = bnB & 63;

  {  // stage m=0
    const int mx0 = d ? 15 : 0;
    *(uint4*)&x_s[0][r0][c0 * 8] =
        *(const uint4*)&rnn16[((size_t)(nnA * 16 + mx0) * 64 + bbA) * 320 + c0 * 8];
    if (tid < 128)
      *(uint4*)&x_s[0][r1][c1 * 8] =
          *(const uint4*)&rnn16[((size_t)(nnB * 16 + mx0) * 64 + bbB) * 320 + c1 * 8];
  }
  __syncthreads();

  for (int m = 0; m < kM; m++) {
    const int mx = d ? (15 - m) : m;
    const int buf = m & 1;
    uint4 pf0, pf1;
    const bool has = (m + 1 < kM);
    if (has) {
      const int mxn = d ? (15 - (m + 1)) : (m + 1);
      pf0 = *(const uint4*)&rnn16[((size_t)(nnA * 16 + mxn) * 64 + bbA) * 320 + c0 * 8];
      if (tid < 128)
        pf1 = *(const uint4*)&rnn16[((size_t)(nnB * 16 + mxn) * 64 + bbB) * 320 + c1 * 8];
    }
    f32x4 aR = (f32x4)(0.f), aZ = (f32x4)(0.f), aNX = (f32x4)(0.f), aNH = (f32x4)(0.f);
#pragma unroll
    for (int kt = 0; kt < 14; kt++) {
      const bf16x8 af = (kt < 10) ? *(const bf16x8*)&x_s[buf][col][kt * 32 + q8]
                                  : *(const bf16x8*)&h_s[col][(kt - 10) * 32 + q8];
      aR = __builtin_amdgcn_mfma_f32_16x16x32_bf16(af, bw[0][kt], aR, 0, 0, 0);
      aZ = __builtin_amdgcn_mfma_f32_16x16x32_bf16(af, bw[1][kt], aZ, 0, 0, 0);
      if (kt < 10) aNX = __builtin_amdgcn_mfma_f32_16x16x32_bf16(af, bw[2][kt], aNX, 0, 0, 0);
      else         aNH = __builtin_amdgcn_mfma_f32_16x16x32_bf16(af, bw[2][kt], aNH, 0, 0, 0);
    }
    __syncthreads();
#pragma unroll
    for (int i = 0; i < 4; i++) {
      const int row = q * 4 + i;
      const float rr = sigm(aR[i] + biR);
      const float zz = sigm(aZ[i] + biZ);
      const float nn2 = tanh_fast(aNX[i] + biNX + rr * (aNH[i] + biNH));
      const float hnew = (1.f - zz) * nn2 + zz * h32r[i];
      h32r[i] = hnew;
      const unsigned short us = f2bf(hnew);
      h_s[row][j] = us;
      hv16[((size_t)(bn0 + row) * kM + mx) * 256 + d * kHH + j] = us;
    }
    if (has) {
      *(uint4*)&x_s[buf ^ 1][r0][c0 * 8] = pf0;
      if (tid < 128) *(uint4*)&x_s[buf ^ 1][r1][c1 * 8] = pf1;
    }
    __syncthreads();
  }
}

// ---------------------------------------------------------------------------
// Fused attention + ctx-logits (validated r10/r11): 512 blocks x 8 n.
__global__ __launch_bounds__(256) void k_attn_ctx(
    const unsigned short* __restrict__ hv16, const unsigned short* __restrict__ ptpack,
    const float* __restrict__ u, const float* __restrict__ w,
    const float* __restrict__ c0p,
    const float* __restrict__ Wp, const float* __restrict__ bp,
    const float* __restrict__ Wk, const float* __restrict__ bk,
    float* __restrict__ clog, float* __restrict__ kslogp) {
  const int tid = threadIdx.x;
  const int wv = tid >> 6, lane = tid & 63, col = lane & 15, q = lane >> 4, q8 = q * 8;
  __shared__ __align__(16) unsigned short hv16s[16][264];
  __shared__ __align__(16) unsigned short Ts16[16][264];
  __shared__ __align__(16) float W2[50][260];
  __shared__ __align__(16) float cs[256];
  __shared__ __align__(16) float us[256], wss[256];
  __shared__ float pu[16][17], pw[16][17];
  __shared__ float uh[16], wh[16], SM[16];
  __shared__ float As[16][17];
  __shared__ float arr[64];
  __shared__ float bps[35], bks[15];
  const float c0 = c0p[0];
  for (int i = tid; i < 35 * 256; i += 256) { const int r = i >> 8, c = i & 255; W2[r][c] = Wp[r * 556 + 300 + c]; }
  for (int i = tid; i < 15 * 256; i += 256) { const int r = i >> 8, c = i & 255; W2[35 + r][c] = Wk[r * 256 + c]; }
  us[tid] = u[tid];
  wss[tid] = w[tid];
  if (tid < 35) bps[tid] = bp[tid];
  else if (tid < 50) bks[tid - 35] = bk[tid - 35];
  bf16x8 bpt[4][8];
#pragma unroll
  for (int i2 = 0; i2 < 4; i2++)
#pragma unroll
    for (int kt = 0; kt < 8; kt++)
      bpt[i2][kt] = *(const bf16x8*)&ptpack[((((size_t)(wv * 4 + i2)) * 8 + kt) * 64 + lane) * 8];

  const int srow = tid >> 4, sci = (tid & 15) * 16;
  { // stage n0
    const unsigned short* src = hv16 + (size_t)(blockIdx.x * 8) * 4096;
#pragma unroll
    for (int k = 0; k < 16; k += 4)
      *(ushort4*)&hv16s[srow][sci + k] = *(const ushort4*)&src[srow * 256 + sci + k];
  }
  __syncthreads();

  for (int ni = 0; ni < 8; ni++) {
    const int n = blockIdx.x * 8 + ni;
    ushort4 pf[4];
    if (ni + 1 < 8) {
      const unsigned short* src = hv16 + (size_t)(n + 1) * 4096;
#pragma unroll
      for (int k2 = 0; k2 < 4; k2++) pf[k2] = *(const ushort4*)&src[srow * 256 + sci + k2 * 4];
    }
    {  // PT GEMM via MFMA
      f32x4 acc4[4];
#pragma unroll
      for (int i2 = 0; i2 < 4; i2++) acc4[i2] = (f32x4)(0.f);
#pragma unroll
      for (int kt = 0; kt < 8; kt++) {
        const bf16x8 af = *(const bf16x8*)&hv16s[col][kt * 32 + q8];
#pragma unroll
        for (int i2 = 0; i2 < 4; i2++)
          acc4[i2] = __builtin_amdgcn_mfma_f32_16x16x32_bf16(af, bpt[i2][kt], acc4[i2], 0, 0, 0);
      }
#pragma unroll
      for (int i2 = 0; i2 < 4; i2++) {
        const int nt = wv * 4 + i2;
#pragma unroll
        for (int i = 0; i < 4; i++) Ts16[q * 4 + i][nt * 16 + col] = f2bf(acc4[i2][i]);
      }
    }
    {  // u/w partial dots (LDS sources)
      const int l = tid >> 4, s = tid & 15;
      float su = 0.f, sw = 0.f;
#pragma unroll
      for (int a0 = 0; a0 < 16; a0++) {
        const int a = s * 16 + a0;
        const float hvv = bf2f(hv16s[l][a]);
        su += hvv * us[a];
        sw += hvv * wss[a];
      }
      pu[l][s] = su; pw[l][s] = sw;
    }
    __syncthreads();
    if (tid < 16) { float s2 = 0.f; for (int s = 0; s < 16; s++) s2 += pu[tid][s]; uh[tid] = s2; }
    else if (tid < 32) { float s2 = 0.f; for (int s = 0; s < 16; s++) s2 += pw[tid - 16][s]; wh[tid - 16] = s2; }
    __syncthreads();
    if (tid < 64) {  // wave 0: score MFMA + softmax
      f32x4 sa = (f32x4)(0.f);
#pragma unroll
      for (int kt = 0; kt < 8; kt++) {
        const bf16x8 af  = *(const bf16x8*)&hv16s[col][kt * 32 + q8];
        const bf16x8 bts = *(const bf16x8*)&Ts16[col][kt * 32 + q8];
        sa = __builtin_amdgcn_mfma_f32_16x16x32_bf16(af, bts, sa, 0, 0, 0);
      }
#pragma unroll
      for (int i = 0; i < 4; i++) {
        const int l = q * 4 + i;
        float sc = sa[i] + c0 + uh[l] + wh[col];
        float mxv = sc;
#pragma unroll
        for (int o = 8; o >= 1; o >>= 1) mxv = fmaxf(mxv, __shfl_xor(mxv, o, 16));
        const float e = __expf(sc - mxv);
        float se = e;
#pragma unroll
        for (int o = 8; o >= 1; o >>= 1) se += __shfl_xor(se, o, 16);
        As[l][col] = e / se;
      }
    }
    __syncthreads();
    if (tid < 16) {
      float s = 0.f;
      for (int l2 = 0; l2 < 16; l2++) s += As[l2][tid];
      SM[tid] = s;
    }
    __syncthreads();
    {  // ctx into LDS (last read of hv16s this iteration)
      float cv = 0.f;
#pragma unroll
      for (int m2 = 0; m2 < 16; m2++) cv += SM[m2] * bf2f(hv16s[m2][tid]);
      cs[tid] = cv;
    }
    __syncthreads();
    if (ni + 1 < 8) {
#pragma unroll
      for (int k2 = 0; k2 < 4; k2++) *(ushort4*)&hv16s[srow][sci + k2 * 4] = pf[k2];
    }
    {  // ctx-logits
      const int o = tid >> 2, s = tid & 3;
      float v = 0.f;
      if (o < 50) {
        for (int k0 = 0; k0 < 64; k0 += 4) {
          const int k = s * 64 + k0;
          const float4 wq = *(const float4*)&W2[o][k];
          const float4 cq = *(const float4*)&cs[k];
          v += wq.x * cq.x + wq.y * cq.y + wq.z * cq.z + wq.w * cq.w;
        }
      }
      v += __shfl_xor(v, 1);
      v += __shfl_xor(v, 2);
      if (o < 50 && s == 0) arr[o] = v;
    }
    __syncthreads();
    if (tid < 35) clog[n * kNP + tid] = arr[tid] + bps[tid];
    if (tid >= 64 && tid < 80) {
      const int t2 = tid - 64;
      float kk = (t2 < 15) ? arr[35 + t2] + bks[t2] : -1e30f;
      float mxv = kk;
#pragma unroll
      for (int off = 8; off >= 1; off >>= 1) mxv = fmaxf(mxv, __shfl_xor(mxv, off, 16));
      const float e = (t2 < 15) ? __expf(kk - mxv) : 0.f;
      float se = e;
#pragma unroll
      for (int off = 8; off >= 1; off >>= 1) se += __shfl_xor(se, off, 16);
      if (t2 < 15) kslogp[n * kNK + t2] = kk - mxv - __logf(se);
    }
    __syncthreads();
  }
}

// ---------------------------------------------------------------------------
// Loss via MFMA (r12 LDS staging) — r13: NO atomics, NO fences. Per-block
// LDS reduction -> one plain float4 partial store; k_final sums partials.
__global__ __launch_bounds__(256, 2) void k_loss_mfma(
    const unsigned short* __restrict__ rnn16,  // [65536][320]
    const unsigned short* __restrict__ bpackL, // [3][10][64][8]
    const float* __restrict__ clog,            // [4096][35]
    const float* __restrict__ ks_logp,         // [4096][15]
    const int* __restrict__ pitches, const int* __restrict__ kss,
    float4* __restrict__ partial) {            // [1024]
  const int tid = threadIdx.x, w = tid >> 6, lane = tid & 63;
  const int col = lane & 15, q = lane >> 4, q8 = q * 8;
  __shared__ __align__(16) unsigned short xls[64][328];
  __shared__ float red[4][4];
  bf16x8 bl[3][10];
#pragma unroll
  for (int nt = 0; nt < 3; nt++)
#pragma unroll
    for (int kt = 0; kt < 10; kt++)
      bl[nt][kt] = *(const bf16x8*)&bpackL[(((size_t)nt * 10 + kt) * 64 + lane) * 8];

  {  // coalesced stage of this block's 64 rows
    const size_t base = (size_t)blockIdx.x * 64;
    for (int i = tid; i < 64 * 40; i += 256) {
      const int r = i / 40, c = i - r * 40;
      *(uint4*)&xls[r][c * 8] = *(const uint4*)&rnn16[(base + r) * 320 + c * 8];
    }
  }
  __syncthreads();

  float sp = 0.f, cp = 0.f, sk = 0.f, ck = 0.f;
  {
    const int rowbase = blockIdx.x * 64 + w * 16;
    f32x4 a0 = (f32x4)(0.f), a1 = (f32x4)(0.f), a2 = (f32x4)(0.f);
#pragma unroll
    for (int kt = 0; kt < 10; kt++) {
      const bf16x8 af = *(const bf16x8*)&xls[w * 16 + col][kt * 32 + q8];
      a0 = __builtin_amdgcn_mfma_f32_16x16x32_bf16(af, bl[0][kt], a0, 0, 0, 0);
      a1 = __builtin_amdgcn_mfma_f32_16x16x32_bf16(af, bl[1][kt], a1, 0, 0, 0);
      a2 = __builtin_amdgcn_mfma_f32_16x16x32_bf16(af, bl[2][kt], a2, 0, 0, 0);
    }
#pragma unroll
    for (int i = 0; i < 4; i++) {
      const int row = rowbase + q * 4 + i;
      const int t = row >> 6, b = row & 63;
      const int bn = b * 64 + (t >> 4);
      const float lg0 = a0[i] + clog[bn * kNP + col];
      const float lg1 = a1[i] + clog[bn * kNP + 16 + col];
      const float lg2 = (col < 3) ? (a2[i] + clog[bn * kNP + 32 + col]) : -1e30f;
      float mx = fmaxf(fmaxf(lg0, lg1), lg2);
#pragma unroll
      for (int o = 8; o >= 1; o >>= 1) mx = fmaxf(mx, __shfl_xor(mx, o, 16));
      float se = __expf(lg0 - mx) + __expf(lg1 - mx) + __expf(lg2 - mx);
#pragma unroll
      for (int o = 8; o >= 1; o >>= 1) se += __shfl_xor(se, o, 16);
      const int tp = pitches[row];
      const float cand = (tp < 16) ? a0[i] : (tp < 32) ? a1[i] : a2[i];
      const float tva = __shfl(cand, (lane & 48) | (tp & 15), 64);
      if (col == 0 && tp != 34) {
        sp += (mx + __logf(se)) - (tva + clog[bn * kNP + tp]);
        cp += 1.f;
      }
      if (col == 1) {
        const int tk = kss[row];
        if (tk != 14) { sk -= ks_logp[bn * kNK + tk]; ck += 1.f; }
      }
    }
  }
#pragma unroll
  for (int o = 32; o >= 1; o >>= 1) {
    sp += __shfl_xor(sp, o, 64);
    cp += __shfl_xor(cp, o, 64);
    sk += __shfl_xor(sk, o, 64);
    ck += __shfl_xor(ck, o, 64);
  }
  if (lane == 0) { red[w][0] = sp; red[w][1] = cp; red[w][2] = sk; red[w][3] = ck; }
  __syncthreads();
  if (tid == 0) {
    float p0 = 0.f, p1 = 0.f, p2 = 0.f, p3 = 0.f;
#pragma unroll
    for (int q2 = 0; q2 < 4; q2++) { p0 += red[q2][0]; p1 += red[q2][1]; p2 += red[q2][2]; p3 += red[q2][3]; }
    partial[blockIdx.x] = make_float4(p0, p1, p2, p3);
  }
}

// final reduction: 1 block, 256 threads, sums partial[1024].
__global__ __launch_bounds__(256) void k_final(const float4* __restrict__ partial,
                                               float* __restrict__ out) {
  const int tid = threadIdx.x, w = tid >> 6, lane = tid & 63;
  __shared__ float4 red[4];
  float s0 = 0.f, s1 = 0.f, s2 = 0.f, s3 = 0.f;
#pragma unroll
  for (int k = 0; k < 4; k++) {
    const float4 p = partial[tid + 256 * k];
    s0 += p.x; s1 += p.y; s2 += p.z; s3 += p.w;
  }
#pragma unroll
  for (int o = 32; o >= 1; o >>= 1) {
    s0 += __shfl_xor(s0, o, 64);
    s1 += __shfl_xor(s1, o, 64);
    s2 += __shfl_xor(s2, o, 64);
    s3 += __shfl_xor(s3, o, 64);
  }
  if (lane == 0) red[w] = make_float4(s0, s1, s2, s3);
  __syncthreads();
  if (tid == 0) {
    float a0 = 0.f, a1 = 0.f, a2 = 0.f, a3 = 0.f;
#pragma unroll
    for (int q = 0; q < 4; q++) { a0 += red[q].x; a1 += red[q].y; a2 += red[q].z; a3 += red[q].w; }
    out[0] = a0 / fmaxf(a1, 1.f) + a2 / fmaxf(a3, 1.f);
  }
}

// ---------------------------------------------------------------------------
extern "C" void kernel_launch(void* const* d_in, const int* in_sizes, int n_in,
                              void* d_out, int out_size, void* d_ws, size_t ws_size,
                              hipStream_t stream) {
  (void)in_sizes; (void)n_in; (void)out_size; (void)ws_size;
  const float* sent    = (const float*)d_in[0];
  const int*   pitches = (const int*)d_in[1];
  const int*   kss     = (const int*)d_in[2];
  const float* mWih_f  = (const float*)d_in[5];
  const float* mWhh_f  = (const float*)d_in[6];
  const float* mbih_f  = (const float*)d_in[7];
  const float* mbhh_f  = (const float*)d_in[8];
  const float* mWih_b  = (const float*)d_in[9];
  const float* mWhh_b  = (const float*)d_in[10];
  const float* mbih_b  = (const float*)d_in[11];
  const float* mbhh_b  = (const float*)d_in[12];
  const float* hWih_f  = (const float*)d_in[13];
  const float* hWhh_f  = (const float*)d_in[14];
  const float* hbih_f  = (const float*)d_in[15];
  const float* hbhh_f  = (const float*)d_in[16];
  const float* hWih_b  = (const float*)d_in[17];
  const float* hWhh_b  = (const float*)d_in[18];
  const float* hbih_b  = (const float*)d_in[19];
  const float* hbhh_b  = (const float*)d_in[20];
  const float* Wq      = (const float*)d_in[21];
  const float* bq      = (const float*)d_in[22];
  const float* Wv      = (const float*)d_in[23];
  const float* bv      = (const float*)d_in[24];
  const float* Wp      = (const float*)d_in[25];
  const float* bp      = (const float*)d_in[26];
  const float* Wk      = (const float*)d_in[27];
  const float* bk      = (const float*)d_in[28];
  float* ws  = (float*)d_ws;
  float* out = (float*)d_out;
  unsigned short* rnn16  = (unsigned short*)(ws + OFF_RNN16);
  unsigned short* hv16   = (unsigned short*)(ws + OFF_HV16);
  unsigned short* ptpack = (unsigned short*)(ws + OFF_PTPACK);
  unsigned short* bpackL = (unsigned short*)(ws + OFF_BPACKL);
  unsigned short* bpack  = (unsigned short*)(ws + OFF_BPACK);
  float* hsave = ws + OFF_HSAVE;
  float4* partial = (float4*)(ws + OFF_PART);

  k_mega<<<213, 640, 0, stream>>>(sent,
                                  mWih_f, mWhh_f, mWih_b, mWhh_b,
                                  mbih_f, mbhh_f, mbih_b, mbhh_b,
                                  hWih_f, hWhh_f, hWih_b, hWhh_b, Wp,
                                  Wq, bq, Wv, bv,
                                  rnn16, bpack, bpackL, ptpack,
                                  ws + OFF_U, ws + OFF_W, ws + OFF_C0,
                                  hsave, 0, 512);
  k_mega<<<128, 640, 0, stream>>>(sent,
                                  mWih_f, mWhh_f, mWih_b, mWhh_b,
                                  mbih_f, mbhh_f, mbih_b, mbhh_b,
                                  hWih_f, hWhh_f, hWih_b, hWhh_b, Wp,
                                  Wq, bq, Wv, bv,
                                  rnn16, bpack, bpackL, ptpack,
                                  ws + OFF_U, ws + OFF_W, ws + OFF_C0,
                                  hsave, 512, 1024);
  k_hier_mfma<<<512, 512, 0, stream>>>(rnn16, bpack,
                                       hbih_f, hbhh_f, hbih_b, hbhh_b, hv16);
  k_attn_ctx<<<512, 256, 0, stream>>>(hv16, ptpack, ws + OFF_U, ws + OFF_W,
                                      ws + OFF_C0, Wp, bp, Wk, bk,
                                      ws + OFF_CLOG, ws + OFF_KSLOGP);
  k_loss_mfma<<<1024, 256, 0, stream>>>(rnn16, bpackL, ws + OFF_CLOG, ws + OFF_KSLOGP,
                                        pitches, kss, partial);
  k_final<<<1, 256, 0, stream>>>(partial, out);
}

// Round 14
// 910.804 us; speedup vs baseline: 1.2660x; 1.0059x over previous
//
#include <hip/hip_runtime.h>
#include <cstddef>

// ---- problem constants ----
constexpr int kT   = 1024;
constexpr int kB   = 64;
constexpr int kDIN = 17;
constexpr int kHM  = 150;   // main hidden (per dir)
constexpr int kHH  = 128;   // hier hidden (per dir)
constexpr int kM   = 16;    // measure length
constexpr int kD2  = 300;   // 2*kHM
constexpr int kNP  = 35;
constexpr int kNK  = 15;

// ---- workspace layout (float offsets, 16-float aligned) ----
constexpr size_t OFF_RNN16  = 0;          // ushort [1024][64][320] = 10,485,760 f
constexpr size_t OFF_HV16   = 10485760;   // ushort [4096][16][256] = 8,388,608 f
constexpr size_t OFF_PART   = 18894848;   // f32 [1024][4] = 4,096 (loss partials)
constexpr size_t OFF_PTPACK = 19988480;   // ushort [16][8][64][8] = 32,768 f
constexpr size_t OFF_U      = 20021248;   // [256]
constexpr size_t OFF_W      = 20021504;   // [256]
constexpr size_t OFF_C0     = 20021760;   // [16]
constexpr size_t OFF_KSLOGP = 20021792;   // [4096][15]
constexpr size_t OFF_CLOG   = 20083232;   // [4096][35]
constexpr size_t OFF_BPACK  = 20318752;   // ushort [2][24][14][64][8] = 172,032 f
constexpr size_t OFF_BPACKL = 20490784;   // ushort [3][10][64][8] = 7,680 f

typedef __bf16 bf16x8 __attribute__((ext_vector_type(8)));
typedef float f32x4 __attribute__((ext_vector_type(4)));

__device__ __forceinline__ unsigned short f2bf(float f) {
  unsigned u = __float_as_uint(f);
  u += 0x7FFFu + ((u >> 16) & 1u);
  return (unsigned short)(u >> 16);
}
__device__ __forceinline__ float bf2f(unsigned short v) {
  return __uint_as_float(((unsigned)v) << 16);
}
__device__ __forceinline__ float sigm(float x) {
  return __builtin_amdgcn_rcpf(1.f + __expf(-x));
}
__device__ __forceinline__ float tanh_fast(float x) {
  return 1.f - 2.f * __builtin_amdgcn_rcpf(__expf(2.f * x) + 1.f);
}

// ---------------------------------------------------------------------------
// MEGA kernel, single phase (validated r10 config, 703 us): blocks 0..127
// main bi-GRU (full 1024 steps); 128..198 repack; 199..211 ptpack; 212 u/w/c0.
// r14: MFMA accumulator chains 2-deep (kt pairs {0,3},{1,4},{2,5}).
__global__ __launch_bounds__(640, 2) void k_mega(
    const float* __restrict__ x,               // [1024][64][17]
    const float* __restrict__ mWih_f, const float* __restrict__ mWhh_f,
    const float* __restrict__ mWih_b, const float* __restrict__ mWhh_b,
    const float* __restrict__ mbih_f, const float* __restrict__ mbhh_f,
    const float* __restrict__ mbih_b, const float* __restrict__ mbhh_b,
    const float* __restrict__ hWih_f, const float* __restrict__ hWhh_f,
    const float* __restrict__ hWih_b, const float* __restrict__ hWhh_b,
    const float* __restrict__ Wp,
    const float* __restrict__ Wq, const float* __restrict__ bq,
    const float* __restrict__ Wv, const float* __restrict__ bv,
    unsigned short* __restrict__ rnn16,        // [1024][64][320]
    unsigned short* __restrict__ bpack,        // [2][24][14][64][8]
    unsigned short* __restrict__ bpackL,       // [3][10][64][8]
    unsigned short* __restrict__ pp,           // ptpack [16][8][64][8]
    float* __restrict__ u, float* __restrict__ w,
    float* __restrict__ c0)
{
  __shared__ __align__(16) unsigned short hx[2][160];
  __shared__ __align__(16) unsigned short hist[2][16][160];
  __shared__ __align__(16) unsigned short xall[kT][32];
  const int blk = blockIdx.x;
  if (blk < 128) {
    // ---------------- main bi-GRU ----------------
    const int d = blk & 1, b = blk >> 1;
    const int tid = threadIdx.x, wv = tid >> 6, lane = tid & 63;
    const int col = lane & 15, q8 = (lane >> 4) * 8;
    for (int i = tid; i < 2 * 160; i += 640) ((unsigned short*)hx)[i] = 0;
    for (int i = tid; i < 2 * 16 * 160; i += 640) ((unsigned short*)hist)[i] = 0;
    for (int i = tid; i < kT * 32; i += 640) {
      const int t = i >> 5, c = i & 31;
      xall[t][c] = (c < kDIN) ? f2bf(x[((size_t)t * kB + b) * kDIN + c])
                              : (unsigned short)0;
    }
    const float* bih = d ? mbih_b : mbih_f;
    const float* bhh = d ? mbhh_b : mbhh_f;
    const float* Wihd = d ? mWih_b : mWih_f;   // [450][17]
    const float* Whhd = d ? mWhh_b : mWhh_f;   // [450][150]
    const int j = wv * 16 + col;
    const bool actv = (lane < 16) && (j < kHM);
    float br = 0.f, bz = 0.f, bnx = 0.f, bnh = 0.f;
    if (actv) {
      br  = bih[j] + bhh[j];
      bz  = bih[150 + j] + bhh[150 + j];
      bnx = bih[300 + j];
      bnh = bhh[300 + j];
    }
    // gather B-frags (vectorized float2 fast path)
    bf16x8 bw[3][6];
    const int gts[3] = { wv, 10 + wv, 20 + wv };
    const int kb = (lane >> 4) * 8;
#pragma unroll
    for (int gi = 0; gi < 3; gi++) {
      const int slot = gts[gi] * 16 + col;
      const int type = slot / 160, jh = slot - type * 160;
      const int row = type * 150 + jh;
      const bool valid = (jh < 150);
#pragma unroll
      for (int kt = 0; kt < 6; kt++) {
        union { bf16x8 v; unsigned short us[8]; } tmp;
        if (kt < 5) {
          const int k0 = kt * 32 + kb;
          if (valid && (k0 + 8 <= 150)) {
#pragma unroll
            for (int p = 0; p < 4; p++) {
              const float2 f2 = *(const float2*)&Whhd[row * 150 + k0 + 2 * p];
              tmp.us[2 * p]     = f2bf(f2.x);
              tmp.us[2 * p + 1] = f2bf(f2.y);
            }
          } else {
#pragma unroll
            for (int jj = 0; jj < 8; jj++) {
              const int k = k0 + jj;
              tmp.us[jj] = (valid && k < 150) ? f2bf(Whhd[row * 150 + k])
                                              : (unsigned short)0;
            }
          }
        } else {
#pragma unroll
          for (int jj = 0; jj < 8; jj++) {
            const int k = kb + jj;
            tmp.us[jj] = (valid && k < 17) ? f2bf(Wihd[row * 17 + k])
                                           : (unsigned short)0;
          }
        }
        bw[gi][kt] = tmp.v;
      }
    }
    float h_old = 0.f;
    __syncthreads();

    for (int t = 0; t < kT; t++) {
      const int tx = d ? (kT - 1 - t) : t;
      const int buf = t & 1;
      bf16x8 afr[6];
#pragma unroll
      for (int kt = 0; kt < 5; kt++) afr[kt] = *(const bf16x8*)&hx[buf][kt * 32 + q8];
      afr[5] = *(const bf16x8*)&xall[tx][q8];
      // 2-deep chains: pairs {0,3},{1,4},{2,5}
      f32x4 aR0 = (f32x4)(0.f), aR1 = (f32x4)(0.f), aR2 = (f32x4)(0.f);
      f32x4 aZ0 = (f32x4)(0.f), aZ1 = (f32x4)(0.f), aZ2 = (f32x4)(0.f);
      f32x4 aN0 = (f32x4)(0.f), aN1 = (f32x4)(0.f), aN2 = (f32x4)(0.f);
      f32x4 aX  = (f32x4)(0.f);
      aR0 = __builtin_amdgcn_mfma_f32_16x16x32_bf16(afr[0], bw[0][0], aR0, 0, 0, 0);
      aZ0 = __builtin_amdgcn_mfma_f32_16x16x32_bf16(afr[0], bw[1][0], aZ0, 0, 0, 0);
      aN0 = __builtin_amdgcn_mfma_f32_16x16x32_bf16(afr[0], bw[2][0], aN0, 0, 0, 0);
      aR1 = __builtin_amdgcn_mfma_f32_16x16x32_bf16(afr[1], bw[0][1], aR1, 0, 0, 0);
      aZ1 = __builtin_amdgcn_mfma_f32_16x16x32_bf16(afr[1], bw[1][1], aZ1, 0, 0, 0);
      aN1 = __builtin_amdgcn_mfma_f32_16x16x32_bf16(afr[1], bw[2][1], aN1, 0, 0, 0);
      aR2 = __builtin_amdgcn_mfma_f32_16x16x32_bf16(afr[2], bw[0][2], aR2, 0, 0, 0);
      aZ2 = __builtin_amdgcn_mfma_f32_16x16x32_bf16(afr[2], bw[1][2], aZ2, 0, 0, 0);
      aN2 = __builtin_amdgcn_mfma_f32_16x16x32_bf16(afr[2], bw[2][2], aN2, 0, 0, 0);
      aR0 = __builtin_amdgcn_mfma_f32_16x16x32_bf16(afr[3], bw[0][3], aR0, 0, 0, 0);
      aZ0 = __builtin_amdgcn_mfma_f32_16x16x32_bf16(afr[3], bw[1][3], aZ0, 0, 0, 0);
      aN0 = __builtin_amdgcn_mfma_f32_16x16x32_bf16(afr[3], bw[2][3], aN0, 0, 0, 0);
      aR1 = __builtin_amdgcn_mfma_f32_16x16x32_bf16(afr[4], bw[0][4], aR1, 0, 0, 0);
      aZ1 = __builtin_amdgcn_mfma_f32_16x16x32_bf16(afr[4], bw[1][4], aZ1, 0, 0, 0);
      aN1 = __builtin_amdgcn_mfma_f32_16x16x32_bf16(afr[4], bw[2][4], aN1, 0, 0, 0);
      aR2 = __builtin_amdgcn_mfma_f32_16x16x32_bf16(afr[5], bw[0][5], aR2, 0, 0, 0);
      aZ2 = __builtin_amdgcn_mfma_f32_16x16x32_bf16(afr[5], bw[1][5], aZ2, 0, 0, 0);
      aX  = __builtin_amdgcn_mfma_f32_16x16x32_bf16(afr[5], bw[2][5], aX, 0, 0, 0);
      if (actv) {
        const float r = sigm(aR0[0] + aR1[0] + aR2[0] + br);
        const float z = sigm(aZ0[0] + aZ1[0] + aZ2[0] + bz);
        const float n = tanh_fast(aX[0] + bnx + r * (aN0[0] + aN1[0] + aN2[0] + bnh));
        h_old = (1.f - z) * n + z * h_old;
        const unsigned short us = f2bf(h_old);
        hx[buf ^ 1][j] = us;
        hist[(t >> 4) & 1][t & 15][j] = us;
      }
      __syncthreads();
      if ((t & 15) == 15) {
        const int hb = (t >> 4) & 1;
        const int toff = tid / 40, ch = tid - toff * 40;
        const int tg = t - 15 + toff;
        const int txg = d ? (kT - 1 - tg) : tg;
        *(ushort4*)&rnn16[((size_t)txg * kB + b) * 320 + d * 160 + ch * 4] =
            *(const ushort4*)&hist[hb][toff][ch * 4];
      }
    }
  } else if (blk < 199) {
    // ---------------- hier + loss weight repack ----------------
    const int sub = threadIdx.x >> 6, lane = threadIdx.x & 63;
    int bid = (blk - 128) * 10 + sub;
    if (bid >= 702) return;
    if (bid < 672) {
      const int kt = bid % 14;
      const int nt = (bid / 14) % 24;
      const int d  = bid / (14 * 24);
      const float* Wih = d ? hWih_b : hWih_f;   // [384][300]
      const float* Whh = d ? hWhh_b : hWhh_f;   // [384][128]
      const int n = nt * 16 + (lane & 15);
      const int kbase = kt * 32 + (lane >> 4) * 8;
      unsigned short* dst = bpack + ((((size_t)d * 24 + nt) * 14 + kt) * 64 + lane) * 8;
#pragma unroll
      for (int jj = 0; jj < 8; jj++) {
        const int k = kbase + jj;
        float f = 0.f;
        if (kt < 10) {
          if (k < 150) f = Wih[n * 300 + k];
          else if (k >= 160 && k < 310) f = Wih[n * 300 + (k - 10)];
        } else {
          f = Whh[n * 128 + (k - 320)];
        }
        dst[jj] = f2bf(f);
      }
    } else {
      bid -= 672;                       // 0..29 = nt*10+kt
      const int kt = bid % 10, nt = bid / 10;
      const int n = nt * 16 + (lane & 15);
      const int kbase = kt * 32 + (lane >> 4) * 8;
      unsigned short* dst = bpackL + (((size_t)bid) * 64 + lane) * 8;
#pragma unroll
      for (int jj = 0; jj < 8; jj++) {
        const int k = kbase + jj;
        float f = 0.f;
        if (n < kNP) {
          if (k < 150) f = Wp[n * 556 + k];
          else if (k >= 160 && k < 310) f = Wp[n * 556 + (k - 10)];
        }
        dst[jj] = f2bf(f);
      }
    }
  } else if (blk < 212) {
    // ---------------- ptpack direct from Wq.Wv ----------------
    const int sub = threadIdx.x >> 6, lane = threadIdx.x & 63;
    const int bid = (blk - 199) * 10 + sub;
    if (bid >= 128) return;
    const int kt = bid & 7, nt = bid >> 3;
    const int c = nt * 16 + (lane & 15);
    const int e0 = kt * 32 + (lane >> 4) * 8;
    float av[8];
#pragma unroll
    for (int jj = 0; jj < 8; jj++) av[jj] = 0.f;
    for (int a = 0; a < 256; a++) {
      const float wq = Wq[a * 256 + c];
#pragma unroll
      for (int jj = 0; jj < 8; jj++) av[jj] += wq * Wv[a * 256 + e0 + jj];
    }
    unsigned short* dst = pp + ((size_t)bid * 64 + lane) * 8;
#pragma unroll
    for (int jj = 0; jj < 8; jj++) dst[jj] = f2bf(av[jj]);
  } else {
    // ---------------- u, w, c0 ----------------
    const int a = threadIdx.x;
    if (a >= 256) return;
    float us = 0.f, ws = 0.f;
    for (int jj = 0; jj < 256; jj++) {
      us += Wq[jj * 256 + a] * bv[jj];
      ws += bq[jj] * Wv[jj * 256 + a];
    }
    u[a] = us; w[a] = ws;
    if (a == 0) {
      float cc = 0.f;
      for (int jj = 0; jj < 256; jj++) cc += bq[jj] * bv[jj];
      c0[0] = cc;
    }
  }
}

// ---------------------------------------------------------------------------
// Hier bi-GRU (validated r11): register-resident B + register prefetch.
__global__ __launch_bounds__(512, 1) void k_hier_mfma(
    const unsigned short* __restrict__ rnn16,  // [1024][64][320]
    const unsigned short* __restrict__ bpack,  // [2][24][14][64][8]
    const float* __restrict__ bihf, const float* __restrict__ bhhf,
    const float* __restrict__ bihb, const float* __restrict__ bhhb,
    unsigned short* __restrict__ hv16)         // [4096][16][256]
{
  const int d = blockIdx.x & 1;
  const int bn0 = (blockIdx.x >> 1) * 16;
  const int tid = threadIdx.x;
  const int w = tid >> 6;          // 0..7
  const int lane = tid & 63;
  const int q = lane >> 4, col = lane & 15, q8 = q * 8;

  __shared__ __align__(16) unsigned short x_s[2][16][328];
  __shared__ __align__(16) unsigned short h_s[16][136];

  for (int i = tid; i < 16 * 136; i += 512) ((unsigned short*)h_s)[i] = 0;
  const float* bih = d ? bihb : bihf;
  const float* bhh = d ? bhhb : bhhf;
  const int j = w * 16 + col;      // 0..127
  const float biR  = bih[j] + bhh[j];
  const float biZ  = bih[128 + j] + bhh[128 + j];
  const float biNX = bih[256 + j];
  const float biNH = bhh[256 + j];
  float h32r[4] = {0.f, 0.f, 0.f, 0.f};

  bf16x8 bw[3][14];
  const unsigned short* bpd = bpack + (size_t)d * 24 * 14 * 64 * 8;
  const int nts[3] = { w, 8 + w, 16 + w };
#pragma unroll
  for (int gi = 0; gi < 3; gi++)
#pragma unroll
    for (int kt = 0; kt < 14; kt++)
      bw[gi][kt] = *(const bf16x8*)&bpd[(((size_t)nts[gi] * 14 + kt) * 64 + lane) * 8];

  const int i0 = tid,        r0 = i0 / 40, c0 = i0 - r0 * 40;
  const int i1 = tid + 512,  r1 = i1 / 40, c1 = i1 - r1 * 40;
  const int bnA = bn0 + r0, bbA = bnA >> 6, nnA = bnA & 63;
  const int bnB = bn0 + r1, bbB = bnB >> 6, nnB = bnB & 63;

  {  // stage m=0
    const int mx0 = d ? 15 : 0;
    *(uint4*)&x_s[0][r0][c0 * 8] =
        *(const uint4*)&rnn16[((size_t)(nnA * 16 + mx0) * 64 + bbA) * 320 + c0 * 8];
    if (tid < 128)
      *(uint4*)&x_s[0][r1][c1 * 8] =
          *(const uint4*)&rnn16[((size_t)(nnB * 16 + mx0) * 64 + bbB) * 320 + c1 * 8];
  }
  __syncthreads();

  for (int m = 0; m < kM; m++) {
    const int mx = d ? (15 - m) : m;
    const int buf = m & 1;
    uint4 pf0, pf1;
    const bool has = (m + 1 < kM);
    if (has) {
      const int mxn = d ? (15 - (m + 1)) : (m + 1);
      pf0 = *(const uint4*)&rnn16[((size_t)(nnA * 16 + mxn) * 64 + bbA) * 320 + c0 * 8];
      if (tid < 128)
        pf1 = *(const uint4*)&rnn16[((size_t)(nnB * 16 + mxn) * 64 + bbB) * 320 + c1 * 8];
    }
    f32x4 aR = (f32x4)(0.f), aZ = (f32x4)(0.f), aNX = (f32x4)(0.f), aNH = (f32x4)(0.f);
#pragma unroll
    for (int kt = 0; kt < 14; kt++) {
      const bf16x8 af = (kt < 10) ? *(const bf16x8*)&x_s[buf][col][kt * 32 + q8]
                                  : *(const bf16x8*)&h_s[col][(kt - 10) * 32 + q8];
      aR = __builtin_amdgcn_mfma_f32_16x16x32_bf16(af, bw[0][kt], aR, 0, 0, 0);
      aZ = __builtin_amdgcn_mfma_f32_16x16x32_bf16(af, bw[1][kt], aZ, 0, 0, 0);
      if (kt < 10) aNX = __builtin_amdgcn_mfma_f32_16x16x32_bf16(af, bw[2][kt], aNX, 0, 0, 0);
      else         aNH = __builtin_amdgcn_mfma_f32_16x16x32_bf16(af, bw[2][kt], aNH, 0, 0, 0);
    }
    __syncthreads();
#pragma unroll
    for (int i = 0; i < 4; i++) {
      const int row = q * 4 + i;
      const float rr = sigm(aR[i] + biR);
      const float zz = sigm(aZ[i] + biZ);
      const float nn2 = tanh_fast(aNX[i] + biNX + rr * (aNH[i] + biNH));
      const float hnew = (1.f - zz) * nn2 + zz * h32r[i];
      h32r[i] = hnew;
      const unsigned short us = f2bf(hnew);
      h_s[row][j] = us;
      hv16[((size_t)(bn0 + row) * kM + mx) * 256 + d * kHH + j] = us;
    }
    if (has) {
      *(uint4*)&x_s[buf ^ 1][r0][c0 * 8] = pf0;
      if (tid < 128) *(uint4*)&x_s[buf ^ 1][r1][c1 * 8] = pf1;
    }
    __syncthreads();
  }
}

// ---------------------------------------------------------------------------
// Fused attention + ctx-logits (validated r10/r11): 512 blocks x 8 n.
__global__ __launch_bounds__(256) void k_attn_ctx(
    const unsigned short* __restrict__ hv16, const unsigned short* __restrict__ ptpack,
    const float* __restrict__ u, const float* __restrict__ w,
    const float* __restrict__ c0p,
    const float* __restrict__ Wp, const float* __restrict__ bp,
    const float* __restrict__ Wk, const float* __restrict__ bk,
    float* __restrict__ clog, float* __restrict__ kslogp) {
  const int tid = threadIdx.x;
  const int wv = tid >> 6, lane = tid & 63, col = lane & 15, q = lane >> 4, q8 = q * 8;
  __shared__ __align__(16) unsigned short hv16s[16][264];
  __shared__ __align__(16) unsigned short Ts16[16][264];
  __shared__ __align__(16) float W2[50][260];
  __shared__ __align__(16) float cs[256];
  __shared__ __align__(16) float us[256], wss[256];
  __shared__ float pu[16][17], pw[16][17];
  __shared__ float uh[16], wh[16], SM[16];
  __shared__ float As[16][17];
  __shared__ float arr[64];
  __shared__ float bps[35], bks[15];
  const float c0 = c0p[0];
  for (int i = tid; i < 35 * 256; i += 256) { const int r = i >> 8, c = i & 255; W2[r][c] = Wp[r * 556 + 300 + c]; }
  for (int i = tid; i < 15 * 256; i += 256) { const int r = i >> 8, c = i & 255; W2[35 + r][c] = Wk[r * 256 + c]; }
  us[tid] = u[tid];
  wss[tid] = w[tid];
  if (tid < 35) bps[tid] = bp[tid];
  else if (tid < 50) bks[tid - 35] = bk[tid - 35];
  bf16x8 bpt[4][8];
#pragma unroll
  for (int i2 = 0; i2 < 4; i2++)
#pragma unroll
    for (int kt = 0; kt < 8; kt++)
      bpt[i2][kt] = *(const bf16x8*)&ptpack[((((size_t)(wv * 4 + i2)) * 8 + kt) * 64 + lane) * 8];

  const int srow = tid >> 4, sci = (tid & 15) * 16;
  { // stage n0
    const unsigned short* src = hv16 + (size_t)(blockIdx.x * 8) * 4096;
#pragma unroll
    for (int k = 0; k < 16; k += 4)
      *(ushort4*)&hv16s[srow][sci + k] = *(const ushort4*)&src[srow * 256 + sci + k];
  }
  __syncthreads();

  for (int ni = 0; ni < 8; ni++) {
    const int n = blockIdx.x * 8 + ni;
    ushort4 pf[4];
    if (ni + 1 < 8) {
      const unsigned short* src = hv16 + (size_t)(n + 1) * 4096;
#pragma unroll
      for (int k2 = 0; k2 < 4; k2++) pf[k2] = *(const ushort4*)&src[srow * 256 + sci + k2 * 4];
    }
    {  // PT GEMM via MFMA
      f32x4 acc4[4];
#pragma unroll
      for (int i2 = 0; i2 < 4; i2++) acc4[i2] = (f32x4)(0.f);
#pragma unroll
      for (int kt = 0; kt < 8; kt++) {
        const bf16x8 af = *(const bf16x8*)&hv16s[col][kt * 32 + q8];
#pragma unroll
        for (int i2 = 0; i2 < 4; i2++)
          acc4[i2] = __builtin_amdgcn_mfma_f32_16x16x32_bf16(af, bpt[i2][kt], acc4[i2], 0, 0, 0);
      }
#pragma unroll
      for (int i2 = 0; i2 < 4; i2++) {
        const int nt = wv * 4 + i2;
#pragma unroll
        for (int i = 0; i < 4; i++) Ts16[q * 4 + i][nt * 16 + col] = f2bf(acc4[i2][i]);
      }
    }
    {  // u/w partial dots (LDS sources)
      const int l = tid >> 4, s = tid & 15;
      float su = 0.f, sw = 0.f;
#pragma unroll
      for (int a0 = 0; a0 < 16; a0++) {
        const int a = s * 16 + a0;
        const float hvv = bf2f(hv16s[l][a]);
        su += hvv * us[a];
        sw += hvv * wss[a];
      }
      pu[l][s] = su; pw[l][s] = sw;
    }
    __syncthreads();
    if (tid < 16) { float s2 = 0.f; for (int s = 0; s < 16; s++) s2 += pu[tid][s]; uh[tid] = s2; }
    else if (tid < 32) { float s2 = 0.f; for (int s = 0; s < 16; s++) s2 += pw[tid - 16][s]; wh[tid - 16] = s2; }
    __syncthreads();
    if (tid < 64) {  // wave 0: score MFMA + softmax
      f32x4 sa = (f32x4)(0.f);
#pragma unroll
      for (int kt = 0; kt < 8; kt++) {
        const bf16x8 af  = *(const bf16x8*)&hv16s[col][kt * 32 + q8];
        const bf16x8 bts = *(const bf16x8*)&Ts16[col][kt * 32 + q8];
        sa = __builtin_amdgcn_mfma_f32_16x16x32_bf16(af, bts, sa, 0, 0, 0);
      }
#pragma unroll
      for (int i = 0; i < 4; i++) {
        const int l = q * 4 + i;
        float sc = sa[i] + c0 + uh[l] + wh[col];
        float mxv = sc;
#pragma unroll
        for (int o = 8; o >= 1; o >>= 1) mxv = fmaxf(mxv, __shfl_xor(mxv, o, 16));
        const float e = __expf(sc - mxv);
        float se = e;
#pragma unroll
        for (int o = 8; o >= 1; o >>= 1) se += __shfl_xor(se, o, 16);
        As[l][col] = e / se;
      }
    }
    __syncthreads();
    if (tid < 16) {
      float s = 0.f;
      for (int l2 = 0; l2 < 16; l2++) s += As[l2][tid];
      SM[tid] = s;
    }
    __syncthreads();
    {  // ctx into LDS (last read of hv16s this iteration)
      float cv = 0.f;
#pragma unroll
      for (int m2 = 0; m2 < 16; m2++) cv += SM[m2] * bf2f(hv16s[m2][tid]);
      cs[tid] = cv;
    }
    __syncthreads();
    if (ni + 1 < 8) {
#pragma unroll
      for (int k2 = 0; k2 < 4; k2++) *(ushort4*)&hv16s[srow][sci + k2 * 4] = pf[k2];
    }
    {  // ctx-logits
      const int o = tid >> 2, s = tid & 3;
      float v = 0.f;
      if (o < 50) {
        for (int k0 = 0; k0 < 64; k0 += 4) {
          const int k = s * 64 + k0;
          const float4 wq = *(const float4*)&W2[o][k];
          const float4 cq = *(const float4*)&cs[k];
          v += wq.x * cq.x + wq.y * cq.y + wq.z * cq.z + wq.w * cq.w;
        }
      }
      v += __shfl_xor(v, 1);
      v += __shfl_xor(v, 2);
      if (o < 50 && s == 0) arr[o] = v;
    }
    __syncthreads();
    if (tid < 35) clog[n * kNP + tid] = arr[tid] + bps[tid];
    if (tid >= 64 && tid < 80) {
      const int t2 = tid - 64;
      float kk = (t2 < 15) ? arr[35 + t2] + bks[t2] : -1e30f;
      float mxv = kk;
#pragma unroll
      for (int off = 8; off >= 1; off >>= 1) mxv = fmaxf(mxv, __shfl_xor(mxv, off, 16));
      const float e = (t2 < 15) ? __expf(kk - mxv) : 0.f;
      float se = e;
#pragma unroll
      for (int off = 8; off >= 1; off >>= 1) se += __shfl_xor(se, off, 16);
      if (t2 < 15) kslogp[n * kNK + t2] = kk - mxv - __logf(se);
    }
    __syncthreads();
  }
}

// ---------------------------------------------------------------------------
// Loss via MFMA (validated r13: LDS staging, atomic-free partials).
__global__ __launch_bounds__(256, 2) void k_loss_mfma(
    const unsigned short* __restrict__ rnn16,  // [65536][320]
    const unsigned short* __restrict__ bpackL, // [3][10][64][8]
    const float* __restrict__ clog,            // [4096][35]
    const float* __restrict__ ks_logp,         // [4096][15]
    const int* __restrict__ pitches, const int* __restrict__ kss,
    float4* __restrict__ partial) {            // [1024]
  const int tid = threadIdx.x, w = tid >> 6, lane = tid & 63;
  const int col = lane & 15, q = lane >> 4, q8 = q * 8;
  __shared__ __align__(16) unsigned short xls[64][328];
  __shared__ float red[4][4];
  bf16x8 bl[3][10];
#pragma unroll
  for (int nt = 0; nt < 3; nt++)
#pragma unroll
    for (int kt = 0; kt < 10; kt++)
      bl[nt][kt] = *(const bf16x8*)&bpackL[(((size_t)nt * 10 + kt) * 64 + lane) * 8];

  {  // coalesced stage of this block's 64 rows
    const size_t base = (size_t)blockIdx.x * 64;
    for (int i = tid; i < 64 * 40; i += 256) {
      const int r = i / 40, c = i - r * 40;
      *(uint4*)&xls[r][c * 8] = *(const uint4*)&rnn16[(base + r) * 320 + c * 8];
    }
  }
  __syncthreads();

  float sp = 0.f, cp = 0.f, sk = 0.f, ck = 0.f;
  {
    const int rowbase = blockIdx.x * 64 + w * 16;
    f32x4 a0 = (f32x4)(0.f), a1 = (f32x4)(0.f), a2 = (f32x4)(0.f);
#pragma unroll
    for (int kt = 0; kt < 10; kt++) {
      const bf16x8 af = *(const bf16x8*)&xls[w * 16 + col][kt * 32 + q8];
      a0 = __builtin_amdgcn_mfma_f32_16x16x32_bf16(af, bl[0][kt], a0, 0, 0, 0);
      a1 = __builtin_amdgcn_mfma_f32_16x16x32_bf16(af, bl[1][kt], a1, 0, 0, 0);
      a2 = __builtin_amdgcn_mfma_f32_16x16x32_bf16(af, bl[2][kt], a2, 0, 0, 0);
    }
#pragma unroll
    for (int i = 0; i < 4; i++) {
      const int row = rowbase + q * 4 + i;
      const int t = row >> 6, b = row & 63;
      const int bn = b * 64 + (t >> 4);
      const float lg0 = a0[i] + clog[bn * kNP + col];
      const float lg1 = a1[i] + clog[bn * kNP + 16 + col];
      const float lg2 = (col < 3) ? (a2[i] + clog[bn * kNP + 32 + col]) : -1e30f;
      float mx = fmaxf(fmaxf(lg0, lg1), lg2);
#pragma unroll
      for (int o = 8; o >= 1; o >>= 1) mx = fmaxf(mx, __shfl_xor(mx, o, 16));
      float se = __expf(lg0 - mx) + __expf(lg1 - mx) + __expf(lg2 - mx);
#pragma unroll
      for (int o = 8; o >= 1; o >>= 1) se += __shfl_xor(se, o, 16);
      const int tp = pitches[row];
      const float cand = (tp < 16) ? a0[i] : (tp < 32) ? a1[i] : a2[i];
      const float tva = __shfl(cand, (lane & 48) | (tp & 15), 64);
      if (col == 0 && tp != 34) {
        sp += (mx + __logf(se)) - (tva + clog[bn * kNP + tp]);
        cp += 1.f;
      }
      if (col == 1) {
        const int tk = kss[row];
        if (tk != 14) { sk -= ks_logp[bn * kNK + tk]; ck += 1.f; }
      }
    }
  }
#pragma unroll
  for (int o = 32; o >= 1; o >>= 1) {
    sp += __shfl_xor(sp, o, 64);
    cp += __shfl_xor(cp, o, 64);
    sk += __shfl_xor(sk, o, 64);
    ck += __shfl_xor(ck, o, 64);
  }
  if (lane == 0) { red[w][0] = sp; red[w][1] = cp; red[w][2] = sk; red[w][3] = ck; }
  __syncthreads();
  if (tid == 0) {
    float p0 = 0.f, p1 = 0.f, p2 = 0.f, p3 = 0.f;
#pragma unroll
    for (int q2 = 0; q2 < 4; q2++) { p0 += red[q2][0]; p1 += red[q2][1]; p2 += red[q2][2]; p3 += red[q2][3]; }
    partial[blockIdx.x] = make_float4(p0, p1, p2, p3);
  }
}

// final reduction: 1 block, 256 threads, sums partial[1024].
__global__ __launch_bounds__(256) void k_final(const float4* __restrict__ partial,
                                               float* __restrict__ out) {
  const int tid = threadIdx.x, w = tid >> 6, lane = tid & 63;
  __shared__ float4 red[4];
  float s0 = 0.f, s1 = 0.f, s2 = 0.f, s3 = 0.f;
#pragma unroll
  for (int k = 0; k < 4; k++) {
    const float4 p = partial[tid + 256 * k];
    s0 += p.x; s1 += p.y; s2 += p.z; s3 += p.w;
  }
#pragma unroll
  for (int o = 32; o >= 1; o >>= 1) {
    s0 += __shfl_xor(s0, o, 64);
    s1 += __shfl_xor(s1, o, 64);
    s2 += __shfl_xor(s2, o, 64);
    s3 += __shfl_xor(s3, o, 64);
  }
  if (lane == 0) red[w] = make_float4(s0, s1, s2, s3);
  __syncthreads();
  if (tid == 0) {
    float a0 = 0.f, a1 = 0.f, a2 = 0.f, a3 = 0.f;
#pragma unroll
    for (int q = 0; q < 4; q++) { a0 += red[q].x; a1 += red[q].y; a2 += red[q].z; a3 += red[q].w; }
    out[0] = a0 / fmaxf(a1, 1.f) + a2 / fmaxf(a3, 1.f);
  }
}

// ---------------------------------------------------------------------------
extern "C" void kernel_launch(void* const* d_in, const int* in_sizes, int n_in,
                              void* d_out, int out_size, void* d_ws, size_t ws_size,
                              hipStream_t stream) {
  (void)in_sizes; (void)n_in; (void)out_size; (void)ws_size;
  const float* sent    = (const float*)d_in[0];
  const int*   pitches = (const int*)d_in[1];
  const int*   kss     = (const int*)d_in[2];
  const float* mWih_f  = (const float*)d_in[5];
  const float* mWhh_f  = (const float*)d_in[6];
  const float* mbih_f  = (const float*)d_in[7];
  const float* mbhh_f  = (const float*)d_in[8];
  const float* mWih_b  = (const float*)d_in[9];
  const float* mWhh_b  = (const float*)d_in[10];
  const float* mbih_b  = (const float*)d_in[11];
  const float* mbhh_b  = (const float*)d_in[12];
  const float* hWih_f  = (const float*)d_in[13];
  const float* hWhh_f  = (const float*)d_in[14];
  const float* hbih_f  = (const float*)d_in[15];
  const float* hbhh_f  = (const float*)d_in[16];
  const float* hWih_b  = (const float*)d_in[17];
  const float* hWhh_b  = (const float*)d_in[18];
  const float* hbih_b  = (const float*)d_in[19];
  const float* hbhh_b  = (const float*)d_in[20];
  const float* Wq      = (const float*)d_in[21];
  const float* bq      = (const float*)d_in[22];
  const float* Wv      = (const float*)d_in[23];
  const float* bv      = (const float*)d_in[24];
  const float* Wp      = (const float*)d_in[25];
  const float* bp      = (const float*)d_in[26];
  const float* Wk      = (const float*)d_in[27];
  const float* bk      = (const float*)d_in[28];
  float* ws  = (float*)d_ws;
  float* out = (float*)d_out;
  unsigned short* rnn16  = (unsigned short*)(ws + OFF_RNN16);
  unsigned short* hv16   = (unsigned short*)(ws + OFF_HV16);
  unsigned short* ptpack = (unsigned short*)(ws + OFF_PTPACK);
  unsigned short* bpackL = (unsigned short*)(ws + OFF_BPACKL);
  unsigned short* bpack  = (unsigned short*)(ws + OFF_BPACK);
  float4* partial = (float4*)(ws + OFF_PART);

  k_mega<<<213, 640, 0, stream>>>(sent,
                                  mWih_f, mWhh_f, mWih_b, mWhh_b,
                                  mbih_f, mbhh_f, mbih_b, mbhh_b,
                                  hWih_f, hWhh_f, hWih_b, hWhh_b, Wp,
                                  Wq, bq, Wv, bv,
                                  rnn16, bpack, bpackL, ptpack,
                                  ws + OFF_U, ws + OFF_W, ws + OFF_C0);
  k_hier_mfma<<<512, 512, 0, stream>>>(rnn16, bpack,
                                       hbih_f, hbhh_f, hbih_b, hbhh_b, hv16);
  k_attn_ctx<<<512, 256, 0, stream>>>(hv16, ptpack, ws + OFF_U, ws + OFF_W,
                                      ws + OFF_C0, Wp, bp, Wk, bk,
                                      ws + OFF_CLOG, ws + OFF_KSLOGP);
  k_loss_mfma<<<1024, 256, 0, stream>>>(rnn16, bpackL, ws + OFF_CLOG, ws + OFF_KSLOGP,
                                        pitches, kss, partial);
  k_final<<<1, 256, 0, stream>>>(partial, out);
}